// Round 10
// baseline (25305.995 us; speedup 1.0000x reference)
//
#include <hip/hip_runtime.h>

#define BATCH  64
#define TT     512
#define IDIM   64
#define HDIM   512
#define NAHEAD 24
#define HB     (HDIM * BATCH)

// ---- encoder_coop LDS layout: scratch + bias ONLY (weights now come from
// global via L1/L2 — see kernel comment). 74 KB < 160 KiB. ----
#define SCR_OFF    0                            // 16*64*17 = 17408
#define GL_OFF     17408                        // 16*64    = 1024
#define BIAS_OFF   18432                        // 16
#define ENC_SMEM_FLOATS 18448
#define ENC_SMEM_BYTES  (ENC_SMEM_FLOATS * 4)   // 73792 B

// ---- decoder_coop LDS layout ----
#define DW_IH    0                              // [8][512]
#define DW_HH    4096                           // [8][512]
#define DSCR     8192                           // [8][64][17] = 8704
#define DGL      16896                          // [8][64] = 512
#define DBIAS    17408                          // 8 (+pad)
#define DRED     17424                          // [32][64] = 2048
#define DMZ      19472                          // [2][64]
#define DCTX     19600                          // [2][64]
#define DEC_SMEM_FLOATS 19728
#define DEC_SMEM_BYTES  (DEC_SMEM_FLOATS * 4)   // 78912 B

typedef float v2f __attribute__((ext_vector_type(2)));

__device__ __forceinline__ float4 ld4(const float* p) {
  return *reinterpret_cast<const float4*>(p);
}
__device__ __forceinline__ float sigm(float x) { return 1.0f / (1.0f + expf(-x)); }

// Agent-scope write-through store for cross-WG data (readers are on other
// XCDs; per-XCD L2s are not coherent). Round-8 lesson: agent-scope LOADS
// bypass the local L2 entirely and cost ~2x — cross-step buffers are
// WRITE-ONCE and read with plain cached loads instead.
__device__ __forceinline__ void AS(float* p, float v) {
  __hip_atomic_store(p, v, __ATOMIC_RELAXED, __HIP_MEMORY_SCOPE_AGENT);
}

// ---------------------------------------------------------------------------
// Flag-array grid barrier (flush-free, RMW-free arrivals). No cache
// maintenance (cg::grid.sync's per-step L2 flush was the round-1 regression).
// Cross-step data is agent-scope stored + vmcnt-drained before the flag
// store, and only read next epoch.
// ---------------------------------------------------------------------------
__device__ __forceinline__ void flag_barrier(unsigned* flags, unsigned* release,
                                             unsigned epoch, int bid) {
  asm volatile("s_waitcnt vmcnt(0)" ::: "memory");
  __syncthreads();
  if (threadIdx.x == 0)
    __hip_atomic_store(&flags[(size_t)bid * 16], epoch,
                       __ATOMIC_RELAXED, __HIP_MEMORY_SCOPE_AGENT);
  asm volatile("" ::: "memory");
  if (bid == 0 && threadIdx.x < 64) {
    const int l = threadIdx.x;
    for (;;) {
      bool ok = true;
#pragma unroll
      for (int i = 0; i < 4; ++i) {
        unsigned v = __hip_atomic_load(&flags[(size_t)(l * 4 + i) * 16],
                                       __ATOMIC_RELAXED, __HIP_MEMORY_SCOPE_AGENT);
        ok &= (v >= epoch);
      }
      if (__all(ok)) break;
      __builtin_amdgcn_s_sleep(1);
    }
    if (threadIdx.x == 0)
      __hip_atomic_store(release, epoch, __ATOMIC_RELAXED,
                         __HIP_MEMORY_SCOPE_AGENT);
  }
  if (threadIdx.x == 0) {
    while (__hip_atomic_load(release, __ATOMIC_RELAXED,
                             __HIP_MEMORY_SCOPE_AGENT) < epoch)
      __builtin_amdgcn_s_sleep(1);
  }
  __syncthreads();
  asm volatile("" ::: "memory");
}

// Stage 8 k-elements for 2 batches (bp, bp+32) as v2f; static indices only.
#define STG8(dst, base, off0)                                          \
  _Pragma("unroll") for (int i = 0; i < 8; ++i) {                      \
    dst[i].x = (base)[((off0) + i) * BATCH];                           \
    dst[i].y = (base)[((off0) + i) * BATCH + 32];                      \
  }

// Weight row index for gate-slot d: r(d) = (d>>1)*HDIM + j0 + (d&1).
// d is compile-time in the unrolled burns, j0 is uniform -> the row offset
// folds to SGPR arithmetic; the only lane-varying part is ks (2 values per
// wave -> 2 broadcast requests, L1-served).
#define WROW(d) ((size_t)((((d) >> 1) * HDIM) + j0 + ((d) & 1)) * HDIM)

// Burn one 8-k S-chunk from GLOBAL weights (L1/L2 cached, off the LDS pipe —
// round-9's 104 ds_read_b128/thread/step serialized on the single LDS pipe).
#define BURN_S(sarr, C0)                                                      \
  do {                                                                        \
    _Pragma("unroll") for (int c = 0; c < 8; c += 4) {                        \
      if (t < TT) {                                                           \
        _Pragma("unroll") for (int d = 0; d < 8; ++d) {                       \
          float4 w = ld4(w_hh0 + WROW(d) + ks * 16 + (C0) + c);               \
          a0[d] += sarr[c]*w.x + sarr[c+1]*w.y + sarr[c+2]*w.z + sarr[c+3]*w.w;\
        }                                                                     \
      }                                                                       \
      if (t >= 1) {                                                           \
        _Pragma("unroll") for (int d = 0; d < 8; ++d) {                       \
          float4 w = ld4(w_ih1 + WROW(d) + ks * 16 + (C0) + c);               \
          a1[d] += sarr[c]*w.x + sarr[c+1]*w.y + sarr[c+2]*w.z + sarr[c+3]*w.w;\
        }                                                                     \
      }                                                                       \
    }                                                                         \
  } while (0)

#define BURN_E(earr, C0)                                                      \
  do {                                                                        \
    if (t >= 1) {                                                             \
      _Pragma("unroll") for (int c = 0; c < 8; c += 4) {                      \
        _Pragma("unroll") for (int d = 0; d < 8; ++d) {                       \
          float4 w = ld4(w_hh1 + WROW(d) + ks * 16 + (C0) + c);               \
          a1[d] += earr[c]*w.x + earr[c+1]*w.y + earr[c+2]*w.z + earr[c+3]*w.w;\
        }                                                                     \
      }                                                                       \
    }                                                                         \
  } while (0)

// ---------------------------------------------------------------------------
// Merged-cell encoder v4: r=2 batch-pairing (round-6 verified; r=4 spills),
// weights read DIRECTLY from global. Per-WG weight slice = 50 KB: mostly
// L1-resident; all 32 WGs/XCD = 1.6 MB, fully L2-resident -> refills never
// touch HBM. This moves ~104 weight reads/thread/step off the LDS pipe
// (which also serves the reduce) onto the otherwise-idle vector-mem pipe.
// LDS now only scratch+bias (74 KB). Everything else identical to round 9.
// ---------------------------------------------------------------------------
__global__ __launch_bounds__(1024, 4)
void encoder_coop(const float* __restrict__ xT,
                  const float* __restrict__ w_ih0, const float* __restrict__ w_hh0,
                  const float* __restrict__ b_ih0, const float* __restrict__ b_hh0,
                  const float* __restrict__ w_ih1, const float* __restrict__ w_hh1,
                  const float* __restrict__ b_ih1, const float* __restrict__ b_hh1,
                  float* __restrict__ seq0,        // [T+1][H][B], slot0 zero
                  float* __restrict__ enc,         // [T+1][H][B], slot0 zero
                  float* __restrict__ cst1,        // [H][B] final L1 c-state
                  unsigned* flags, unsigned* release)
{
  extern __shared__ float smem[];
  const int tid  = threadIdx.x;
  const int bid  = blockIdx.x;
  const int j0   = bid * 2;
  const int lane = tid & 63;
  const int wv   = tid >> 6;                     // 0..15 (scratch slot)
  const int bp   = tid & 31;                     // batch pair {bp, bp+32}
  const int ks   = tid >> 5;                     // 0..31 (k-slice of 16)

  if (tid < 16) {
    int d = tid & 7;
    size_t r = (size_t)((d >> 1) * HDIM + j0 + (d & 1));
    smem[BIAS_OFF + tid] = (tid < 8) ? (b_ih0[r] + b_hh0[r])
                                     : (b_ih1[r] + b_hh1[r]);
  }
  __syncthreads();

  float c0 = 0.f;                                // valid for tid < 128
  float c1 = 0.f;                                // valid for 128 <= tid < 256

  for (int t = 0; t <= TT; ++t) {
    const float* sp = seq0 + (size_t)t * HB + (size_t)(ks * 16) * BATCH + bp;
    const float* ep = enc + (size_t)(t >= 1 ? t - 1 : 0) * HB
                          + (size_t)(ks * 16) * BATCH + bp;

    v2f sA[8], sB[8], eA[8], eB[8];
    v2f xv[4];

    STG8(sA, sp, 0);
    STG8(sB, sp, 8);
    if (t < TT && ks < 16) {
      const float* xp = xT + (size_t)t * IDIM * BATCH
                           + (size_t)(ks * 4) * BATCH + bp;
#pragma unroll
      for (int i = 0; i < 4; ++i) {
        xv[i].x = xp[i * BATCH];
        xv[i].y = xp[i * BATCH + 32];
      }
    }

    v2f a0[8], a1[8];
#pragma unroll
    for (int d = 0; d < 8; ++d) { a0[d] = 0.f; a1[d] = 0.f; }

    if (t < TT && ks < 16) {
#pragma unroll
      for (int d = 0; d < 8; ++d) {
        float4 w = ld4(w_ih0 +
            (size_t)(((d >> 1) * HDIM) + j0 + (d & 1)) * IDIM + ks * 4);
        a0[d] += xv[0]*w.x + xv[1]*w.y + xv[2]*w.z + xv[3]*w.w;
      }
    }

    BURN_S(sA, 0);
    if (t >= 1) STG8(eA, ep, 0);
    BURN_S(sB, 8);
    if (t >= 1) STG8(eB, ep, 8);
    BURN_E(eA, 0);
    BURN_E(eB, 8);

#pragma unroll
    for (int d = 0; d < 8; ++d) {
      float m0x = a0[d].x + __shfl_xor(a0[d].x, 32);
      float m0y = a0[d].y + __shfl_xor(a0[d].y, 32);
      smem[SCR_OFF + (d * 64 + lane) * 17 + wv] = (lane >= 32) ? m0y : m0x;
      float m1x = a1[d].x + __shfl_xor(a1[d].x, 32);
      float m1y = a1[d].y + __shfl_xor(a1[d].y, 32);
      smem[SCR_OFF + ((8 + d) * 64 + lane) * 17 + wv] = (lane >= 32) ? m1y : m1x;
    }
    __syncthreads();

    {
      const int dd = tid >> 6, bb = tid & 63;
      float s = 0.f;
#pragma unroll
      for (int i = 0; i < 16; ++i) s += smem[SCR_OFF + (dd * 64 + bb) * 17 + i];
      smem[GL_OFF + dd * 64 + bb] = s + smem[BIAS_OFF + dd];
    }
    __syncthreads();

    if (tid < 256) {
      const int bb = tid & 63, u = tid >> 6;
      if (u < 2) {
        if (t < TT) {
          const int cl = u;
          float gi = smem[GL_OFF + (0 + cl) * 64 + bb];
          float gf = smem[GL_OFF + (2 + cl) * 64 + bb];
          float gg = smem[GL_OFF + (4 + cl) * 64 + bb];
          float go = smem[GL_OFF + (6 + cl) * 64 + bb];
          float cn = sigm(gf) * c0 + sigm(gi) * tanhf(gg);
          float hn = sigm(go) * tanhf(cn);
          c0 = cn;
          AS(&seq0[(size_t)(t + 1) * HB + (size_t)(j0 + cl) * BATCH + bb], hn);
        }
      } else {
        if (t >= 1) {
          const int cl = u - 2;
          float gi = smem[GL_OFF + (8 + 0 + cl) * 64 + bb];
          float gf = smem[GL_OFF + (8 + 2 + cl) * 64 + bb];
          float gg = smem[GL_OFF + (8 + 4 + cl) * 64 + bb];
          float go = smem[GL_OFF + (8 + 6 + cl) * 64 + bb];
          float cn = sigm(gf) * c1 + sigm(gi) * tanhf(gg);
          float hn = sigm(go) * tanhf(cn);
          c1 = cn;
          AS(&enc[(size_t)t * HB + (size_t)(j0 + cl) * BATCH + bb], hn);
        }
      }
    }

    if (t < TT) flag_barrier(flags, release, (unsigned)(t + 1), bid);
  }

  if (tid >= 128 && tid < 256)
    cst1[(size_t)(j0 + ((tid >> 6) - 2)) * BATCH + (tid & 63)] = c1;
}

// ---------------------------------------------------------------------------
// Fused decoder v2 (round-9 verified): step-indexed write-once buffers,
// plain cached loads, agent-scope stores + flag barriers.
// ---------------------------------------------------------------------------
__global__ __launch_bounds__(1024, 4)
void decoder_coop(const float* __restrict__ enc,
                  const float* __restrict__ w_ihd, const float* __restrict__ w_hhd,
                  const float* __restrict__ b_ihd, const float* __restrict__ b_hhd,
                  const float* __restrict__ w_fc, const float* __restrict__ b_fc,
                  const float* __restrict__ cst1_in,
                  float* __restrict__ scores,      // [NAHEAD][T][B]
                  float* __restrict__ xi,          // [NAHEAD][H][B]
                  float* __restrict__ hstep,       // [NAHEAD][H][B]
                  float* __restrict__ out,
                  unsigned* flags, unsigned* release)
{
  extern __shared__ float sm[];
  const int tid = threadIdx.x;
  const int bid = blockIdx.x;
  const int j0  = bid * 2;
  const int b   = tid & 63;

  for (int idx = tid; idx < 8 * HDIM; idx += 1024) {
    int d = idx >> 9, k = idx & 511;
    size_t r = (size_t)((d >> 1) * HDIM + j0 + (d & 1));
    sm[DW_IH + idx] = w_ihd[r * HDIM + k];
    sm[DW_HH + idx] = w_hhd[r * HDIM + k];
  }
  if (tid < 8) {
    size_t r = (size_t)((tid >> 1) * HDIM + j0 + (tid & 1));
    sm[DBIAS + tid] = b_ihd[r] + b_hhd[r];
  }
  __syncthreads();

  float c = 0.f;
  if (tid < 128)
    c = cst1_in[(size_t)(j0 + (tid >> 6)) * BATCH + (tid & 63)];

  unsigned ep = 0;

  for (int s = 0; s < NAHEAD; ++s) {
    const float* h_cur = (s == 0) ? enc + (size_t)TT * HB
                                  : hstep + (size_t)(s - 1) * HB;
    float* sc_s = scores + (size_t)s * TT * BATCH;
    float* xi_s = xi + (size_t)s * HB;

    // ---- phase 1: scores[t][b] for t = bid*2, bid*2+1 (plain loads) ----
    {
      const int tl = tid >> 9;                   // 0..1
      const int k8 = (tid >> 6) & 7;             // 0..7
      const int t  = bid * 2 + tl;
      const float* e  = enc + (size_t)(t + 1) * HB + (size_t)(k8 * 64) * BATCH + b;
      const float* hr = h_cur + (size_t)(k8 * 64) * BATCH + b;
      float a = 0.f;
#pragma unroll 4
      for (int k = 0; k < 64; ++k)
        a += hr[(size_t)k * BATCH] * e[(size_t)k * BATCH];
      sm[DRED + (tl * 8 + k8) * 64 + b] = a;
      __syncthreads();
      if (tid < 128) {
        const int tl2 = tid >> 6;
        float s8 = 0.f;
#pragma unroll
        for (int i = 0; i < 8; ++i) s8 += sm[DRED + (tl2 * 8 + i) * 64 + b];
        AS(&sc_s[(size_t)(bid * 2 + tl2) * BATCH + b], s8);
      }
    }
    flag_barrier(flags, release, ++ep, bid);

    // ---- phase 2: softmax + ctx (cols j0,j0+1) + pred_{s-1} ----
    {
      const int ts = tid >> 6;                   // 0..15, 32-wide slices
      float sc[32];
#pragma unroll
      for (int i = 0; i < 32; ++i)
        sc[i] = sc_s[(size_t)(ts * 32 + i) * BATCH + b];
      float m = -1e30f;
#pragma unroll
      for (int i = 0; i < 32; ++i) m = fmaxf(m, sc[i]);
      sm[DRED + ts * 64 + b] = m;
      __syncthreads();
      if (tid < 64) {
        float mm = sm[DRED + b];
#pragma unroll
        for (int i = 1; i < 16; ++i) mm = fmaxf(mm, sm[DRED + i * 64 + b]);
        sm[DMZ + b] = mm;
      }
      __syncthreads();
      m = sm[DMZ + b];
      float z = 0.f;
#pragma unroll
      for (int i = 0; i < 32; ++i) z += expf(sc[i] - m);
      sm[DRED + (16 + ts) * 64 + b] = z;
      __syncthreads();
      if (tid < 64) {
        float zz = 0.f;
#pragma unroll
        for (int i = 0; i < 16; ++i) zz += sm[DRED + (16 + i) * 64 + b];
        sm[DMZ + 64 + b] = 1.f / zz;
      }
      __syncthreads();
      const float rZ = sm[DMZ + 64 + b];

      float a0 = 0.f, a1 = 0.f;
      const float* eb = enc + HB + (size_t)j0 * BATCH + b;
      for (int i = 0; i < 32; ++i) {
        int t = ts * 32 + i;
        float p = expf(sc[i] - m) * rZ;
        a0 += p * eb[(size_t)t * HB];
        a1 += p * eb[(size_t)t * HB + BATCH];
      }
      __syncthreads();
      sm[DRED + ts * 64 + b] = a0;
      sm[DRED + (16 + ts) * 64 + b] = a1;
      __syncthreads();
      if (tid < 128) {
        const int cl = tid >> 6;
        float cs = 0.f;
#pragma unroll
        for (int i = 0; i < 16; ++i) cs += sm[DRED + (cl * 16 + i) * 64 + b];
        sm[DCTX + cl * 64 + b] = cs;
      }

      float p0 = 0.f, p1 = 0.f;
      if (s >= 1) {
        const float* w0 = w_fc + (size_t)j0 * HDIM + ts * 32;
        const float* w1 = w0 + HDIM;
        const float* hr = h_cur + (size_t)(ts * 32) * BATCH + b;
#pragma unroll 2
        for (int k = 0; k < 32; k += 4) {
          float4 wa = ld4(w0 + k), wb = ld4(w1 + k);
          float h0 = hr[(k + 0) * BATCH], h1 = hr[(k + 1) * BATCH];
          float h2 = hr[(k + 2) * BATCH], h3 = hr[(k + 3) * BATCH];
          p0 += wa.x*h0 + wa.y*h1 + wa.z*h2 + wa.w*h3;
          p1 += wb.x*h0 + wb.y*h1 + wb.z*h2 + wb.w*h3;
        }
      }
      __syncthreads();
      sm[DRED + ts * 64 + b] = p0;
      sm[DRED + (16 + ts) * 64 + b] = p1;
      __syncthreads();
      if (tid < 128) {
        const int cl = tid >> 6;
        const int cc = j0 + cl;
        float pred = 0.f;
        if (s >= 1) {
#pragma unroll
          for (int i = 0; i < 16; ++i) pred += sm[DRED + (cl * 16 + i) * 64 + b];
          pred += b_fc[cc];
          out[((size_t)b * NAHEAD + (s - 1)) * HDIM + cc] = pred;
        }
        AS(&xi_s[(size_t)cc * BATCH + b], sm[DCTX + cl * 64 + b] + pred);
      }
    }
    flag_barrier(flags, release, ++ep, bid);

    // ---- phase 3: gates (xi_s ; h_cur) -> hstep[s], c in register ----
    {
      const int ks = tid >> 6;                   // 0..15
      float acc[8] = {0.f,0.f,0.f,0.f,0.f,0.f,0.f,0.f};
      if (ks < 8) {
        const float* ip = xi_s + (size_t)(ks * 64) * BATCH + b;
#pragma unroll 2
        for (int k = 0; k < 64; k += 4) {
          float x0 = ip[(k + 0) * BATCH], x1 = ip[(k + 1) * BATCH];
          float x2 = ip[(k + 2) * BATCH], x3 = ip[(k + 3) * BATCH];
#pragma unroll
          for (int d = 0; d < 8; ++d) {
            float4 w = ld4(&sm[DW_IH + d * HDIM + ks * 64 + k]);
            acc[d] += x0*w.x + x1*w.y + x2*w.z + x3*w.w;
          }
        }
      } else {
        const float* hp = h_cur + (size_t)((ks - 8) * 64) * BATCH + b;
#pragma unroll 2
        for (int k = 0; k < 64; k += 4) {
          float h0 = hp[(k + 0) * BATCH], h1 = hp[(k + 1) * BATCH];
          float h2 = hp[(k + 2) * BATCH], h3 = hp[(k + 3) * BATCH];
#pragma unroll
          for (int d = 0; d < 8; ++d) {
            float4 w = ld4(&sm[DW_HH + d * HDIM + (ks - 8) * 64 + k]);
            acc[d] += h0*w.x + h1*w.y + h2*w.z + h3*w.w;
          }
        }
      }
#pragma unroll
      for (int d = 0; d < 8; ++d) sm[DSCR + (d * 64 + b) * 17 + ks] = acc[d];
      __syncthreads();
      if (tid < 512) {
        const int dd = tid >> 6, bb = tid & 63;
        float s16 = 0.f;
#pragma unroll
        for (int i = 0; i < 16; ++i) s16 += sm[DSCR + (dd * 64 + bb) * 17 + i];
        sm[DGL + dd * 64 + bb] = s16 + sm[DBIAS + dd];
      }
      __syncthreads();
      if (tid < 128) {
        const int bb = tid & 63, cl = tid >> 6;
        float gi = sm[DGL + (0 + cl) * 64 + bb];
        float gf = sm[DGL + (2 + cl) * 64 + bb];
        float gg = sm[DGL + (4 + cl) * 64 + bb];
        float go = sm[DGL + (6 + cl) * 64 + bb];
        float cn = sigm(gf) * c + sigm(gi) * tanhf(gg);
        float hn = sigm(go) * tanhf(cn);
        c = cn;
        AS(&hstep[(size_t)s * HB + (size_t)(j0 + cl) * BATCH + bb], hn);
      }
    }
    flag_barrier(flags, release, ++ep, bid);
  }

  // ---- final prediction row (srow = 23) from hstep[NAHEAD-1] ----
  {
    const float* h_fin = hstep + (size_t)(NAHEAD - 1) * HB;
    const int ts = tid >> 6;
    float p0 = 0.f, p1 = 0.f;
    const float* w0 = w_fc + (size_t)j0 * HDIM + ts * 32;
    const float* w1 = w0 + HDIM;
    const float* hr = h_fin + (size_t)(ts * 32) * BATCH + b;
#pragma unroll 2
    for (int k = 0; k < 32; k += 4) {
      float4 wa = ld4(w0 + k), wb = ld4(w1 + k);
      float h0 = hr[(k + 0) * BATCH], h1 = hr[(k + 1) * BATCH];
      float h2 = hr[(k + 2) * BATCH], h3 = hr[(k + 3) * BATCH];
      p0 += wa.x*h0 + wa.y*h1 + wa.z*h2 + wa.w*h3;
      p1 += wb.x*h0 + wb.y*h1 + wb.z*h2 + wb.w*h3;
    }
    __syncthreads();
    sm[DRED + ts * 64 + b] = p0;
    sm[DRED + (16 + ts) * 64 + b] = p1;
    __syncthreads();
    if (tid < 128) {
      const int cl = tid >> 6;
      const int cc = j0 + cl;
      float p = 0.f;
#pragma unroll
      for (int i = 0; i < 16; ++i) p += sm[DRED + (cl * 16 + i) * 64 + b];
      out[((size_t)b * NAHEAD + (NAHEAD - 1)) * HDIM + cc] = p + b_fc[cc];
    }
  }
}

// ---------------------------------------------------------------------------
// Original global-weight cell (kept for fallback paths).
// ---------------------------------------------------------------------------
template <int DIN0>
__device__ __forceinline__ void cell_tile2(
    int j0, const float* __restrict__ in0,
    const float* __restrict__ h_in,
    const float* __restrict__ w_ih,
    const float* __restrict__ w_hh,
    const float* __restrict__ b_ih, const float* __restrict__ b_hh,
    float* __restrict__ c_state,
    float* __restrict__ h_out,
    float* __restrict__ sm)
{
  const int tid = threadIdx.x;
  const int b  = tid & 63;
  const int ks = tid >> 6;
  constexpr int K  = DIN0 + HDIM;
  constexpr int KS = K / 16;
  const int k0 = ks * KS, k1 = k0 + KS;
  const int a0 = (k0 < DIN0) ? k0 : DIN0;
  const int a1 = (k1 < DIN0) ? k1 : DIN0;
  const int c0 = (k0 > DIN0) ? k0 - DIN0 : 0;
  const int c1 = (k1 > DIN0) ? k1 - DIN0 : 0;

  const float* wi = w_ih + (size_t)j0 * DIN0;
  const float* wh = w_hh + (size_t)j0 * HDIM;

  float acc[8] = {0.f, 0.f, 0.f, 0.f, 0.f, 0.f, 0.f, 0.f};

#pragma unroll 2
  for (int k = a0; k < a1; k += 4) {
    float x0 = in0[(k + 0) * BATCH + b];
    float x1 = in0[(k + 1) * BATCH + b];
    float x2 = in0[(k + 2) * BATCH + b];
    float x3 = in0[(k + 3) * BATCH + b];
#pragma unroll
    for (int d = 0; d < 8; ++d) {
      float4 w = ld4(wi + (size_t)((d >> 1) * HDIM + (d & 1)) * DIN0 + k);
      acc[d] += x0 * w.x + x1 * w.y + x2 * w.z + x3 * w.w;
    }
  }
#pragma unroll 2
  for (int k = c0; k < c1; k += 4) {
    float h0 = h_in[(k + 0) * BATCH + b];
    float h1 = h_in[(k + 1) * BATCH + b];
    float h2 = h_in[(k + 2) * BATCH + b];
    float h3 = h_in[(k + 3) * BATCH + b];
#pragma unroll
    for (int d = 0; d < 8; ++d) {
      float4 w = ld4(wh + (size_t)((d >> 1) * HDIM + (d & 1)) * HDIM + k);
      acc[d] += h0 * w.x + h1 * w.y + h2 * w.z + h3 * w.w;
    }
  }

  float* gl = sm + 8 * 64 * 17;
#pragma unroll
  for (int d = 0; d < 8; ++d) sm[(d * 64 + b) * 17 + ks] = acc[d];
  __syncthreads();

  if (tid < 512) {
    const int dd = tid >> 6, bb = tid & 63;
    float s = 0.f;
#pragma unroll
    for (int i = 0; i < 16; ++i) s += sm[(dd * 64 + bb) * 17 + i];
    const int r = (dd >> 1) * HDIM + j0 + (dd & 1);
    gl[dd * 64 + bb] = s + b_ih[r] + b_hh[r];
  }
  __syncthreads();

  if (tid < 128) {
    const int bb = tid & 63, cl = tid >> 6;
    const int jc = j0 + cl;
    float gi = gl[(0 + cl) * 64 + bb];
    float gf = gl[(2 + cl) * 64 + bb];
    float gg = gl[(4 + cl) * 64 + bb];
    float go = gl[(6 + cl) * 64 + bb];
    float cold = c_state[(size_t)jc * BATCH + bb];
    float cn = sigm(gf) * cold + sigm(gi) * tanhf(gg);
    float hn = sigm(go) * tanhf(cn);
    c_state[(size_t)jc * BATCH + bb] = cn;
    h_out[(size_t)jc * BATCH + bb] = hn;
  }
  __syncthreads();
}

__global__ __launch_bounds__(1024, 1)
void lstm_step(int t,
               const float* __restrict__ xT,
               const float* __restrict__ w_ih0, const float* __restrict__ w_hh0,
               const float* __restrict__ b_ih0, const float* __restrict__ b_hh0,
               const float* __restrict__ w_ih1, const float* __restrict__ w_hh1,
               const float* __restrict__ b_ih1, const float* __restrict__ b_hh1,
               float* __restrict__ seq0, float* __restrict__ enc,
               float* __restrict__ cst0, float* __restrict__ cst1)
{
  __shared__ float sm[8 * 64 * 17 + 8 * 64];
  const int j0 = blockIdx.x * 2;
  if (t < TT)
    cell_tile2<IDIM>(j0, xT + (size_t)t * IDIM * BATCH,
                     seq0 + (size_t)t * HB,
                     w_ih0, w_hh0, b_ih0, b_hh0,
                     cst0, seq0 + (size_t)(t + 1) * HB, sm);
  if (t >= 1)
    cell_tile2<HDIM>(j0, seq0 + (size_t)t * HB,
                     enc + (size_t)(t - 1) * HB,
                     w_ih1, w_hh1, b_ih1, b_hh1,
                     cst1, enc + (size_t)t * HB, sm);
}

__global__ __launch_bounds__(1024, 1)
void dec_gates(const float* __restrict__ xi, const float* __restrict__ h_cur,
               const float* __restrict__ w_ih, const float* __restrict__ w_hh,
               const float* __restrict__ b_ih, const float* __restrict__ b_hh,
               float* __restrict__ cst, float* __restrict__ h_out)
{
  __shared__ float sm[8 * 64 * 17 + 8 * 64];
  cell_tile2<HDIM>(blockIdx.x * 2, xi, h_cur, w_ih, w_hh, b_ih, b_hh,
                   cst, h_out, sm);
}

__global__ __launch_bounds__(512, 2)
void attn_scores(const float* __restrict__ enc,
                 const float* __restrict__ h_cur,
                 float* __restrict__ scores)
{
  __shared__ float red[2][8][64];
  const int tid = threadIdx.x;
  const int b  = tid & 63;
  const int ks = tid >> 6;
  const int t0 = blockIdx.x * 2;
  const float* e0 = enc + (size_t)(t0 + 1) * HB + ks * 64 * BATCH;
  const float* e1 = e0 + HB;
  const float* hr = h_cur + ks * 64 * BATCH;
  float a0 = 0.f, a1 = 0.f;
#pragma unroll 4
  for (int k = 0; k < 64; ++k) {
    float hv = hr[k * BATCH + b];
    a0 += hv * e0[k * BATCH + b];
    a1 += hv * e1[k * BATCH + b];
  }
  red[0][ks][b] = a0;
  red[1][ks][b] = a1;
  __syncthreads();
  if (tid < 128) {
    int tl = tid >> 6;
    float s = 0.f;
#pragma unroll
    for (int i = 0; i < 8; ++i) s += red[tl][i][b];
    scores[(size_t)(t0 + tl) * BATCH + b] = s;
  }
}

__global__ __launch_bounds__(512, 2)
void attn_ctx(const float* __restrict__ enc,
              const float* __restrict__ scores,
              const float* __restrict__ h_cur,
              const float* __restrict__ w_fc, const float* __restrict__ b_fc,
              float* __restrict__ xi,
              float* __restrict__ out,
              int s)
{
  __shared__ float red[8][2][64];
  __shared__ float mz[2][64];
  __shared__ float ctxv[2][64];
  const int tid = threadIdx.x;
  const int b  = tid & 63;
  const int ts = tid >> 6;
  const int hc0 = blockIdx.x * 2;

  float m = -1e30f;
  for (int t = ts * 64; t < ts * 64 + 64; ++t)
    m = fmaxf(m, scores[(size_t)t * BATCH + b]);
  red[ts][0][b] = m;
  __syncthreads();
  if (tid < 64) {
    float mm = red[0][0][b];
#pragma unroll
    for (int i = 1; i < 8; ++i) mm = fmaxf(mm, red[i][0][b]);
    mz[0][b] = mm;
  }
  __syncthreads();
  m = mz[0][b];
  float z = 0.f;
  for (int t = ts * 64; t < ts * 64 + 64; ++t)
    z += expf(scores[(size_t)t * BATCH + b] - m);
  red[ts][1][b] = z;
  __syncthreads();
  if (tid < 64) {
    float zz = 0.f;
#pragma unroll
    for (int i = 0; i < 8; ++i) zz += red[i][1][b];
    mz[1][b] = 1.f / zz;
  }
  __syncthreads();
  const float rZ = mz[1][b];

  float a0 = 0.f, a1 = 0.f;
  const float* eb = enc + HB + (size_t)hc0 * BATCH + b;
  for (int t = ts * 64; t < ts * 64 + 64; ++t) {
    float p = expf(scores[(size_t)t * BATCH + b] - m) * rZ;
    a0 += p * eb[(size_t)t * HB];
    a1 += p * eb[(size_t)t * HB + BATCH];
  }
  __syncthreads();
  red[ts][0][b] = a0;
  red[ts][1][b] = a1;
  __syncthreads();
  if (tid < 128) {
    int cl = tid >> 6;
    float c = 0.f;
#pragma unroll
    for (int i = 0; i < 8; ++i) c += red[i][cl][b];
    ctxv[cl][b] = c;
  }

  float p0 = 0.f, p1 = 0.f;
  if (s >= 1) {
    const float* w0 = w_fc + (size_t)hc0 * HDIM + ts * 64;
    const float* w1 = w0 + HDIM;
    const float* hr = h_cur + ts * 64 * BATCH;
#pragma unroll 2
    for (int k = 0; k < 64; k += 4) {
      float4 wa = ld4(w0 + k), wb = ld4(w1 + k);
      float h0 = hr[(k + 0) * BATCH + b], h1 = hr[(k + 1) * BATCH + b];
      float h2 = hr[(k + 2) * BATCH + b], h3 = hr[(k + 3) * BATCH + b];
      p0 += wa.x * h0 + wa.y * h1 + wa.z * h2 + wa.w * h3;
      p1 += wb.x * h0 + wb.y * h1 + wb.z * h2 + wb.w * h3;
    }
  }
  __syncthreads();
  red[ts][0][b] = p0;
  red[ts][1][b] = p1;
  __syncthreads();
  if (tid < 128) {
    int cl = tid >> 6;
    int cc = hc0 + cl;
    float pred = 0.f;
    if (s >= 1) {
#pragma unroll
      for (int i = 0; i < 8; ++i) pred += red[i][cl][b];
      pred += b_fc[cc];
      out[((size_t)b * NAHEAD + (s - 1)) * HDIM + cc] = pred;
    }
    xi[(size_t)cc * BATCH + b] = ctxv[cl][b] + pred;
  }
}

__global__ __launch_bounds__(512, 2)
void fc_out(const float* __restrict__ h, const float* __restrict__ w_fc,
            const float* __restrict__ b_fc, float* __restrict__ out, int srow)
{
  __shared__ float red[8][2][64];
  const int tid = threadIdx.x;
  const int b  = tid & 63;
  const int ks = tid >> 6;
  const int cc0 = blockIdx.x * 2;
  const float* w0 = w_fc + (size_t)cc0 * HDIM + ks * 64;
  const float* w1 = w0 + HDIM;
  const float* hr = h + ks * 64 * BATCH;
  float p0 = 0.f, p1 = 0.f;
#pragma unroll 2
  for (int k = 0; k < 64; k += 4) {
    float4 wa = ld4(w0 + k), wb = ld4(w1 + k);
    float h0 = hr[(k + 0) * BATCH + b], h1 = hr[(k + 1) * BATCH + b];
    float h2 = hr[(k + 2) * BATCH + b], h3 = hr[(k + 3) * BATCH + b];
    p0 += wa.x * h0 + wa.y * h1 + wa.z * h2 + wa.w * h3;
    p1 += wb.x * h0 + wb.y * h1 + wb.z * h2 + wb.w * h3;
  }
  red[ks][0][b] = p0;
  red[ks][1][b] = p1;
  __syncthreads();
  if (tid < 128) {
    int cl = tid >> 6;
    int cc = cc0 + cl;
    float p = 0.f;
#pragma unroll
    for (int i = 0; i < 8; ++i) p += red[i][cl][b];
    out[((size_t)b * NAHEAD + srow) * HDIM + cc] = p + b_fc[cc];
  }
}

__global__ __launch_bounds__(256)
void transpose_x(const float* __restrict__ x, float* __restrict__ xT)
{
  __shared__ float tile[64][65];
  const int t = blockIdx.x;
  const int lane = threadIdx.x & 63;
  const int w    = threadIdx.x >> 6;
#pragma unroll
  for (int ii = 0; ii < 16; ++ii) {
    int b = w * 16 + ii;
    tile[b][lane] = x[((size_t)b * TT + t) * IDIM + lane];
  }
  __syncthreads();
#pragma unroll
  for (int ii = 0; ii < 16; ++ii) {
    int i = w * 16 + ii;
    xT[((size_t)t * IDIM + i) * BATCH + lane] = tile[lane][i];
  }
}

// ---------------------------------------------------------------------------
extern "C" void kernel_launch(void* const* d_in, const int* in_sizes, int n_in,
                              void* d_out, int out_size, void* d_ws, size_t ws_size,
                              hipStream_t stream) {
  const float* x     = (const float*)d_in[0];
  const float* w_ih0 = (const float*)d_in[1];
  const float* w_hh0 = (const float*)d_in[2];
  const float* b_ih0 = (const float*)d_in[3];
  const float* b_hh0 = (const float*)d_in[4];
  const float* w_ih1 = (const float*)d_in[5];
  const float* w_hh1 = (const float*)d_in[6];
  const float* b_ih1 = (const float*)d_in[7];
  const float* b_hh1 = (const float*)d_in[8];
  const float* w_ihd = (const float*)d_in[9];
  const float* w_hhd = (const float*)d_in[10];
  const float* b_ihd = (const float*)d_in[11];
  const float* b_hhd = (const float*)d_in[12];
  const float* w_fc  = (const float*)d_in[13];
  const float* b_fc  = (const float*)d_in[14];
  float* out = (float*)d_out;

  char* ws = (char*)d_ws;
  size_t off = 0;
  auto alloc = [&](size_t bytes) -> void* {
    void* p = ws + off;
    off += (bytes + 255) & ~(size_t)255;
    return p;
  };

  float* cst0 = (float*)alloc((size_t)HB * 4);            // zero (fallback)
  float* cst1 = (float*)alloc((size_t)HB * 4);            // final L1 c-state
  float* seq0 = (float*)alloc((size_t)(TT + 1) * HB * 4); // slot0 zero
  float* enc  = (float*)alloc((size_t)(TT + 1) * HB * 4); // slot0 zero
  float* xT   = (float*)alloc((size_t)TT * IDIM * BATCH * 4);
  float* scores = (float*)alloc((size_t)NAHEAD * TT * BATCH * 4); // per-step
  float* xi     = (float*)alloc((size_t)NAHEAD * HB * 4);         // per-step
  float* hstep  = (float*)alloc((size_t)NAHEAD * HB * 4);         // per-step
  unsigned* flags    = (unsigned*)alloc(256 * 16 * 4);    // encoder barrier
  unsigned* release  = (unsigned*)alloc(256);
  unsigned* flags2   = (unsigned*)alloc(256 * 16 * 4);    // decoder barrier
  unsigned* release2 = (unsigned*)alloc(256);
  (void)ws_size; (void)in_sizes; (void)n_in; (void)out_size;

  hipMemsetAsync(cst0, 0, (size_t)HB * 4 * 2, stream);    // cst0+cst1
  hipMemsetAsync(seq0, 0, (size_t)HB * 4, stream);
  hipMemsetAsync(enc,  0, (size_t)HB * 4, stream);
  hipMemsetAsync(flags, 0, 256 * 16 * 4, stream);
  hipMemsetAsync(release, 0, 256, stream);
  hipMemsetAsync(flags2, 0, 256 * 16 * 4, stream);
  hipMemsetAsync(release2, 0, 256, stream);

  transpose_x<<<TT, 256, 0, stream>>>(x, xT);

  static bool attr_set = false;
  if (!attr_set) {
    hipFuncSetAttribute(reinterpret_cast<const void*>(encoder_coop),
                        hipFuncAttributeMaxDynamicSharedMemorySize,
                        ENC_SMEM_BYTES);
    hipFuncSetAttribute(reinterpret_cast<const void*>(decoder_coop),
                        hipFuncAttributeMaxDynamicSharedMemorySize,
                        DEC_SMEM_BYTES);
    attr_set = true;
  }

  // ---- encoder: ONE cooperative kernel, global-cached weights ----
  void* args[] = {
    (void*)&xT,
    (void*)&w_ih0, (void*)&w_hh0, (void*)&b_ih0, (void*)&b_hh0,
    (void*)&w_ih1, (void*)&w_hh1, (void*)&b_ih1, (void*)&b_hh1,
    (void*)&seq0, (void*)&enc, (void*)&cst1, (void*)&flags, (void*)&release
  };
  hipError_t cerr = hipLaunchCooperativeKernel(
      reinterpret_cast<void*>(encoder_coop), dim3(256), dim3(1024),
      args, (unsigned)ENC_SMEM_BYTES, stream);
  if (cerr != hipSuccess) {
    for (int t = 0; t <= TT; ++t) {
      lstm_step<<<256, 1024, 0, stream>>>(
          t, xT, w_ih0, w_hh0, b_ih0, b_hh0,
          w_ih1, w_hh1, b_ih1, b_hh1, seq0, enc, cst0, cst1);
    }
  }

  // ---- decoder: ONE cooperative kernel, step-indexed buffers ----
  void* dargs[] = {
    (void*)&enc, (void*)&w_ihd, (void*)&w_hhd, (void*)&b_ihd, (void*)&b_hhd,
    (void*)&w_fc, (void*)&b_fc, (void*)&cst1,
    (void*)&scores, (void*)&xi, (void*)&hstep, (void*)&out,
    (void*)&flags2, (void*)&release2
  };
  hipError_t derr = hipLaunchCooperativeKernel(
      reinterpret_cast<void*>(decoder_coop), dim3(256), dim3(1024),
      dargs, (unsigned)DEC_SMEM_BYTES, stream);
  if (derr != hipSuccess) {
    // fallback: launch-based decoder reusing slot 0 / slots 0,1
    const float* h_cur = enc + (size_t)TT * HB;
    for (int s = 0; s < NAHEAD; ++s) {
      attn_scores<<<256, 512, 0, stream>>>(enc, h_cur, scores);
      attn_ctx<<<256, 512, 0, stream>>>(enc, scores, h_cur, w_fc, b_fc,
                                        xi, out, s);
      float* h_nxt = hstep + (size_t)(s & 1) * HB;
      dec_gates<<<256, 1024, 0, stream>>>(xi, h_cur, w_ihd, w_hhd,
                                          b_ihd, b_hhd, cst1, h_nxt);
      h_cur = h_nxt;
    }
    fc_out<<<256, 512, 0, stream>>>(h_cur, w_fc, b_fc, out, NAHEAD - 1);
  }
}

// Round 11
// 15545.534 us; speedup vs baseline: 1.6279x; 1.6279x over previous
//
#include <hip/hip_runtime.h>

#define BATCH  64
#define TT     512
#define IDIM   64
#define HDIM   512
#define NAHEAD 24
#define HB     (HDIM * BATCH)

// ---- encoder_coop LDS layout (1 column per WG, 512 WGs, 2 WGs/CU) ----
#define E_WIH0   0                              // [4][64]  = 256
#define E_WHH0   256                            // [4][512] = 2048
#define E_WIH1   2304
#define E_WHH1   4352
#define E_SCR    6400                           // [8][64][17] = 8704
#define E_GL     15104                          // [8][64] = 512
#define E_BIAS   15616                          // 8 (+8 pad)
#define ENC_SMEM_FLOATS 15632
#define ENC_SMEM_BYTES  (ENC_SMEM_FLOATS * 4)   // 62528 B; x2 = 125 KB/CU OK

// ---- decoder_coop LDS layout (unchanged, round-9 verified) ----
#define DW_IH    0                              // [8][512]
#define DW_HH    4096                           // [8][512]
#define DSCR     8192                           // [8][64][17] = 8704
#define DGL      16896                          // [8][64] = 512
#define DBIAS    17408                          // 8 (+pad)
#define DRED     17424                          // [32][64] = 2048
#define DMZ      19472                          // [2][64]
#define DCTX     19600                          // [2][64]
#define DEC_SMEM_FLOATS 19728
#define DEC_SMEM_BYTES  (DEC_SMEM_FLOATS * 4)   // 78912 B

typedef float v2f __attribute__((ext_vector_type(2)));

__device__ __forceinline__ float4 ld4(const float* p) {
  return *reinterpret_cast<const float4*>(p);
}
__device__ __forceinline__ float sigm(float x) { return 1.0f / (1.0f + expf(-x)); }

// Agent-scope write-through store for cross-WG data. Round-8 lesson:
// agent-scope LOADS bypass local L2 (2x cost) — cross-step buffers are
// WRITE-ONCE and read with plain cached loads. Round-10 lesson: weights must
// stay in LDS (global-weight burns spilled: 45 GB scratch traffic).
__device__ __forceinline__ void AS(float* p, float v) {
  __hip_atomic_store(p, v, __ATOMIC_RELAXED, __HIP_MEMORY_SCOPE_AGENT);
}

// ---------------------------------------------------------------------------
// Flag-array grid barrier (flush-free, RMW-free arrivals), NWG workgroups.
// ---------------------------------------------------------------------------
template <int NWG>
__device__ __forceinline__ void flag_barrier(unsigned* flags, unsigned* release,
                                             unsigned epoch, int bid) {
  asm volatile("s_waitcnt vmcnt(0)" ::: "memory");
  __syncthreads();
  if (threadIdx.x == 0)
    __hip_atomic_store(&flags[(size_t)bid * 16], epoch,
                       __ATOMIC_RELAXED, __HIP_MEMORY_SCOPE_AGENT);
  asm volatile("" ::: "memory");
  if (bid == 0 && threadIdx.x < 64) {
    const int l = threadIdx.x;
    for (;;) {
      bool ok = true;
#pragma unroll
      for (int i = 0; i < NWG / 64; ++i) {
        unsigned v = __hip_atomic_load(&flags[(size_t)(l * (NWG / 64) + i) * 16],
                                       __ATOMIC_RELAXED, __HIP_MEMORY_SCOPE_AGENT);
        ok &= (v >= epoch);
      }
      if (__all(ok)) break;
      __builtin_amdgcn_s_sleep(1);
    }
    if (threadIdx.x == 0)
      __hip_atomic_store(release, epoch, __ATOMIC_RELAXED,
                         __HIP_MEMORY_SCOPE_AGENT);
  }
  if (threadIdx.x == 0) {
    while (__hip_atomic_load(release, __ATOMIC_RELAXED,
                             __HIP_MEMORY_SCOPE_AGENT) < epoch)
      __builtin_amdgcn_s_sleep(1);
  }
  __syncthreads();
  asm volatile("" ::: "memory");
}

// Stage 8 k-elements for 2 batches (bp, bp+32) as v2f; static indices only.
#define STG8(dst, base, off0)                                          \
  _Pragma("unroll") for (int i = 0; i < 8; ++i) {                      \
    dst[i].x = (base)[((off0) + i) * BATCH];                           \
    dst[i].y = (base)[((off0) + i) * BATCH + 32];                      \
  }

// Burn one 8-k S-chunk: a0 += sv.whh0 (t<TT, 4 gates), a1 += sv.wih1 (t>=1).
#define BURN_S(sarr, C0)                                                      \
  do {                                                                        \
    _Pragma("unroll") for (int c = 0; c < 8; c += 4) {                        \
      if (t < TT) {                                                           \
        _Pragma("unroll") for (int d = 0; d < 4; ++d) {                       \
          float4 w = ld4(&smem[E_WHH0 + d * HDIM + ks * 16 + (C0) + c]);      \
          a0[d] += sarr[c]*w.x + sarr[c+1]*w.y + sarr[c+2]*w.z + sarr[c+3]*w.w;\
        }                                                                     \
      }                                                                       \
      if (t >= 1) {                                                           \
        _Pragma("unroll") for (int d = 0; d < 4; ++d) {                       \
          float4 w = ld4(&smem[E_WIH1 + d * HDIM + ks * 16 + (C0) + c]);      \
          a1[d] += sarr[c]*w.x + sarr[c+1]*w.y + sarr[c+2]*w.z + sarr[c+3]*w.w;\
        }                                                                     \
      }                                                                       \
    }                                                                         \
  } while (0)

#define BURN_E(earr, C0)                                                      \
  do {                                                                        \
    if (t >= 1) {                                                             \
      _Pragma("unroll") for (int c = 0; c < 8; c += 4) {                      \
        _Pragma("unroll") for (int d = 0; d < 4; ++d) {                       \
          float4 w = ld4(&smem[E_WHH1 + d * HDIM + ks * 16 + (C0) + c]);      \
          a1[d] += earr[c]*w.x + earr[c+1]*w.y + earr[c+2]*w.z + earr[c+3]*w.w;\
        }                                                                     \
      }                                                                       \
    }                                                                         \
  } while (0)

// ---------------------------------------------------------------------------
// Merged-cell encoder v5: 512 WGs x 1024 threads, ONE h-column per WG ->
// 2 WGs/CU = 32 waves/CU (8/SIMD, HW max) vs round-9's 16 waves/CU.
// Per-CU FMA/LDS totals unchanged; latency hiding doubles (round-9 counters:
// VALU 43%, ~40% stall at Occupancy 49%). Cell structure/macros identical to
// round 9 (r=2 batch pairs, LDS weights, shfl merge, stride-17 scratch);
// only the geometry (1 col -> 4 gate rows per cell, 8 accs) changes.
// __launch_bounds__(1024,8) pins VGPR<=64 (8 waves/SIMD budget).
// ---------------------------------------------------------------------------
__global__ __launch_bounds__(1024, 8)
void encoder_coop(const float* __restrict__ xT,
                  const float* __restrict__ w_ih0, const float* __restrict__ w_hh0,
                  const float* __restrict__ b_ih0, const float* __restrict__ b_hh0,
                  const float* __restrict__ w_ih1, const float* __restrict__ w_hh1,
                  const float* __restrict__ b_ih1, const float* __restrict__ b_hh1,
                  float* __restrict__ seq0,        // [T+1][H][B], slot0 zero
                  float* __restrict__ enc,         // [T+1][H][B], slot0 zero
                  float* __restrict__ cst1,        // [H][B] final L1 c-state
                  unsigned* flags, unsigned* release)
{
  extern __shared__ float smem[];
  const int tid  = threadIdx.x;
  const int bid  = blockIdx.x;
  const int j    = bid;                          // this WG's h-column
  const int lane = tid & 63;
  const int wv   = tid >> 6;                     // 0..15 (scratch slot)
  const int bp   = tid & 31;                     // batch pair {bp, bp+32}
  const int ks   = tid >> 5;                     // 0..31 (k-slice of 16)

  // ---- one-time weight staging: gate g row = g*HDIM + j ----
  for (int idx = tid; idx < 4 * IDIM; idx += 1024) {
    int d = idx >> 6, k = idx & 63;
    smem[E_WIH0 + idx] = w_ih0[(size_t)(d * HDIM + j) * IDIM + k];
  }
  for (int idx = tid; idx < 4 * HDIM; idx += 1024) {
    int d = idx >> 9, k = idx & 511;
    size_t r = (size_t)(d * HDIM + j);
    smem[E_WHH0 + idx] = w_hh0[r * HDIM + k];
    smem[E_WIH1 + idx] = w_ih1[r * HDIM + k];
    smem[E_WHH1 + idx] = w_hh1[r * HDIM + k];
  }
  if (tid < 8) {
    int d = tid & 3;
    size_t r = (size_t)(d * HDIM + j);
    smem[E_BIAS + tid] = (tid < 4) ? (b_ih0[r] + b_hh0[r])
                                   : (b_ih1[r] + b_hh1[r]);
  }
  __syncthreads();

  float c0 = 0.f;                                // valid for tid < 64
  float c1 = 0.f;                                // valid for 64 <= tid < 128

  for (int t = 0; t <= TT; ++t) {
    const float* sp = seq0 + (size_t)t * HB + (size_t)(ks * 16) * BATCH + bp;
    const float* ep = enc + (size_t)(t >= 1 ? t - 1 : 0) * HB
                          + (size_t)(ks * 16) * BATCH + bp;

    v2f sA[8], sB[8], eA[8], eB[8];
    v2f xv[4];

    STG8(sA, sp, 0);
    STG8(sB, sp, 8);
    if (t < TT && ks < 16) {
      const float* xp = xT + (size_t)t * IDIM * BATCH
                           + (size_t)(ks * 4) * BATCH + bp;
#pragma unroll
      for (int i = 0; i < 4; ++i) {
        xv[i].x = xp[i * BATCH];
        xv[i].y = xp[i * BATCH + 32];
      }
    }

    v2f a0[4], a1[4];
#pragma unroll
    for (int d = 0; d < 4; ++d) { a0[d] = 0.f; a1[d] = 0.f; }

    if (t < TT && ks < 16) {
#pragma unroll
      for (int d = 0; d < 4; ++d) {
        float4 w = ld4(&smem[E_WIH0 + d * IDIM + ks * 4]);
        a0[d] += xv[0]*w.x + xv[1]*w.y + xv[2]*w.z + xv[3]*w.w;
      }
    }

    BURN_S(sA, 0);
    if (t >= 1) STG8(eA, ep, 0);
    BURN_S(sB, 8);
    if (t >= 1) STG8(eB, ep, 8);
    BURN_E(eA, 0);
    BURN_E(eB, 8);

    // ---- merge the wave's two k-slices, write scratch [8][64][17] ----
#pragma unroll
    for (int d = 0; d < 4; ++d) {
      float m0x = a0[d].x + __shfl_xor(a0[d].x, 32);
      float m0y = a0[d].y + __shfl_xor(a0[d].y, 32);
      smem[E_SCR + (d * 64 + lane) * 17 + wv] = (lane >= 32) ? m0y : m0x;
      float m1x = a1[d].x + __shfl_xor(a1[d].x, 32);
      float m1y = a1[d].y + __shfl_xor(a1[d].y, 32);
      smem[E_SCR + ((4 + d) * 64 + lane) * 17 + wv] = (lane >= 32) ? m1y : m1x;
    }
    __syncthreads();

    if (tid < 512) {                             // one (dd,bb) each, dd 0..7
      const int dd = tid >> 6, bb = tid & 63;
      float s = 0.f;
#pragma unroll
      for (int i = 0; i < 16; ++i) s += smem[E_SCR + (dd * 64 + bb) * 17 + i];
      smem[E_GL + dd * 64 + bb] = s + smem[E_BIAS + dd];
    }
    __syncthreads();

    // ---- cell updates: tid<64 L0, 64..127 L1 (gates i,f,g,o = dd 0..3) ----
    if (tid < 128) {
      const int bb = tid & 63;
      if (tid < 64) {
        if (t < TT) {
          float gi = smem[E_GL + 0 * 64 + bb];
          float gf = smem[E_GL + 1 * 64 + bb];
          float gg = smem[E_GL + 2 * 64 + bb];
          float go = smem[E_GL + 3 * 64 + bb];
          float cn = sigm(gf) * c0 + sigm(gi) * tanhf(gg);
          float hn = sigm(go) * tanhf(cn);
          c0 = cn;
          AS(&seq0[(size_t)(t + 1) * HB + (size_t)j * BATCH + bb], hn);
        }
      } else {
        if (t >= 1) {
          float gi = smem[E_GL + 4 * 64 + bb];
          float gf = smem[E_GL + 5 * 64 + bb];
          float gg = smem[E_GL + 6 * 64 + bb];
          float go = smem[E_GL + 7 * 64 + bb];
          float cn = sigm(gf) * c1 + sigm(gi) * tanhf(gg);
          float hn = sigm(go) * tanhf(cn);
          c1 = cn;
          AS(&enc[(size_t)t * HB + (size_t)j * BATCH + bb], hn);
        }
      }
    }

    if (t < TT) flag_barrier<512>(flags, release, (unsigned)(t + 1), bid);
  }

  if (tid >= 64 && tid < 128)                    // decoder continues this c
    cst1[(size_t)j * BATCH + (tid & 63)] = c1;
}

// ---------------------------------------------------------------------------
// Fused decoder v2 (round-9 verified, byte-identical): step-indexed
// write-once buffers, plain cached loads, agent-scope stores + flag barriers.
// ---------------------------------------------------------------------------
__global__ __launch_bounds__(1024, 4)
void decoder_coop(const float* __restrict__ enc,
                  const float* __restrict__ w_ihd, const float* __restrict__ w_hhd,
                  const float* __restrict__ b_ihd, const float* __restrict__ b_hhd,
                  const float* __restrict__ w_fc, const float* __restrict__ b_fc,
                  const float* __restrict__ cst1_in,
                  float* __restrict__ scores,      // [NAHEAD][T][B]
                  float* __restrict__ xi,          // [NAHEAD][H][B]
                  float* __restrict__ hstep,       // [NAHEAD][H][B]
                  float* __restrict__ out,
                  unsigned* flags, unsigned* release)
{
  extern __shared__ float sm[];
  const int tid = threadIdx.x;
  const int bid = blockIdx.x;
  const int j0  = bid * 2;
  const int b   = tid & 63;

  for (int idx = tid; idx < 8 * HDIM; idx += 1024) {
    int d = idx >> 9, k = idx & 511;
    size_t r = (size_t)((d >> 1) * HDIM + j0 + (d & 1));
    sm[DW_IH + idx] = w_ihd[r * HDIM + k];
    sm[DW_HH + idx] = w_hhd[r * HDIM + k];
  }
  if (tid < 8) {
    size_t r = (size_t)((tid >> 1) * HDIM + j0 + (tid & 1));
    sm[DBIAS + tid] = b_ihd[r] + b_hhd[r];
  }
  __syncthreads();

  float c = 0.f;
  if (tid < 128)
    c = cst1_in[(size_t)(j0 + (tid >> 6)) * BATCH + (tid & 63)];

  unsigned ep = 0;

  for (int s = 0; s < NAHEAD; ++s) {
    const float* h_cur = (s == 0) ? enc + (size_t)TT * HB
                                  : hstep + (size_t)(s - 1) * HB;
    float* sc_s = scores + (size_t)s * TT * BATCH;
    float* xi_s = xi + (size_t)s * HB;

    // ---- phase 1: scores[t][b] for t = bid*2, bid*2+1 (plain loads) ----
    {
      const int tl = tid >> 9;                   // 0..1
      const int k8 = (tid >> 6) & 7;             // 0..7
      const int t  = bid * 2 + tl;
      const float* e  = enc + (size_t)(t + 1) * HB + (size_t)(k8 * 64) * BATCH + b;
      const float* hr = h_cur + (size_t)(k8 * 64) * BATCH + b;
      float a = 0.f;
#pragma unroll 4
      for (int k = 0; k < 64; ++k)
        a += hr[(size_t)k * BATCH] * e[(size_t)k * BATCH];
      sm[DRED + (tl * 8 + k8) * 64 + b] = a;
      __syncthreads();
      if (tid < 128) {
        const int tl2 = tid >> 6;
        float s8 = 0.f;
#pragma unroll
        for (int i = 0; i < 8; ++i) s8 += sm[DRED + (tl2 * 8 + i) * 64 + b];
        AS(&sc_s[(size_t)(bid * 2 + tl2) * BATCH + b], s8);
      }
    }
    flag_barrier<256>(flags, release, ++ep, bid);

    // ---- phase 2: softmax + ctx (cols j0,j0+1) + pred_{s-1} ----
    {
      const int ts = tid >> 6;                   // 0..15, 32-wide slices
      float sc[32];
#pragma unroll
      for (int i = 0; i < 32; ++i)
        sc[i] = sc_s[(size_t)(ts * 32 + i) * BATCH + b];
      float m = -1e30f;
#pragma unroll
      for (int i = 0; i < 32; ++i) m = fmaxf(m, sc[i]);
      sm[DRED + ts * 64 + b] = m;
      __syncthreads();
      if (tid < 64) {
        float mm = sm[DRED + b];
#pragma unroll
        for (int i = 1; i < 16; ++i) mm = fmaxf(mm, sm[DRED + i * 64 + b]);
        sm[DMZ + b] = mm;
      }
      __syncthreads();
      m = sm[DMZ + b];
      float z = 0.f;
#pragma unroll
      for (int i = 0; i < 32; ++i) z += expf(sc[i] - m);
      sm[DRED + (16 + ts) * 64 + b] = z;
      __syncthreads();
      if (tid < 64) {
        float zz = 0.f;
#pragma unroll
        for (int i = 0; i < 16; ++i) zz += sm[DRED + (16 + i) * 64 + b];
        sm[DMZ + 64 + b] = 1.f / zz;
      }
      __syncthreads();
      const float rZ = sm[DMZ + 64 + b];

      float a0 = 0.f, a1 = 0.f;
      const float* eb = enc + HB + (size_t)j0 * BATCH + b;
      for (int i = 0; i < 32; ++i) {
        int t = ts * 32 + i;
        float p = expf(sc[i] - m) * rZ;
        a0 += p * eb[(size_t)t * HB];
        a1 += p * eb[(size_t)t * HB + BATCH];
      }
      __syncthreads();
      sm[DRED + ts * 64 + b] = a0;
      sm[DRED + (16 + ts) * 64 + b] = a1;
      __syncthreads();
      if (tid < 128) {
        const int cl = tid >> 6;
        float cs = 0.f;
#pragma unroll
        for (int i = 0; i < 16; ++i) cs += sm[DRED + (cl * 16 + i) * 64 + b];
        sm[DCTX + cl * 64 + b] = cs;
      }

      float p0 = 0.f, p1 = 0.f;
      if (s >= 1) {
        const float* w0 = w_fc + (size_t)j0 * HDIM + ts * 32;
        const float* w1 = w0 + HDIM;
        const float* hr = h_cur + (size_t)(ts * 32) * BATCH + b;
#pragma unroll 2
        for (int k = 0; k < 32; k += 4) {
          float4 wa = ld4(w0 + k), wb = ld4(w1 + k);
          float h0 = hr[(k + 0) * BATCH], h1 = hr[(k + 1) * BATCH];
          float h2 = hr[(k + 2) * BATCH], h3 = hr[(k + 3) * BATCH];
          p0 += wa.x*h0 + wa.y*h1 + wa.z*h2 + wa.w*h3;
          p1 += wb.x*h0 + wb.y*h1 + wb.z*h2 + wb.w*h3;
        }
      }
      __syncthreads();
      sm[DRED + ts * 64 + b] = p0;
      sm[DRED + (16 + ts) * 64 + b] = p1;
      __syncthreads();
      if (tid < 128) {
        const int cl = tid >> 6;
        const int cc = j0 + cl;
        float pred = 0.f;
        if (s >= 1) {
#pragma unroll
          for (int i = 0; i < 16; ++i) pred += sm[DRED + (cl * 16 + i) * 64 + b];
          pred += b_fc[cc];
          out[((size_t)b * NAHEAD + (s - 1)) * HDIM + cc] = pred;
        }
        AS(&xi_s[(size_t)cc * BATCH + b], sm[DCTX + cl * 64 + b] + pred);
      }
    }
    flag_barrier<256>(flags, release, ++ep, bid);

    // ---- phase 3: gates (xi_s ; h_cur) -> hstep[s], c in register ----
    {
      const int ks = tid >> 6;                   // 0..15
      float acc[8] = {0.f,0.f,0.f,0.f,0.f,0.f,0.f,0.f};
      if (ks < 8) {
        const float* ip = xi_s + (size_t)(ks * 64) * BATCH + b;
#pragma unroll 2
        for (int k = 0; k < 64; k += 4) {
          float x0 = ip[(k + 0) * BATCH], x1 = ip[(k + 1) * BATCH];
          float x2 = ip[(k + 2) * BATCH], x3 = ip[(k + 3) * BATCH];
#pragma unroll
          for (int d = 0; d < 8; ++d) {
            float4 w = ld4(&sm[DW_IH + d * HDIM + ks * 64 + k]);
            acc[d] += x0*w.x + x1*w.y + x2*w.z + x3*w.w;
          }
        }
      } else {
        const float* hp = h_cur + (size_t)((ks - 8) * 64) * BATCH + b;
#pragma unroll 2
        for (int k = 0; k < 64; k += 4) {
          float h0 = hp[(k + 0) * BATCH], h1 = hp[(k + 1) * BATCH];
          float h2 = hp[(k + 2) * BATCH], h3 = hp[(k + 3) * BATCH];
#pragma unroll
          for (int d = 0; d < 8; ++d) {
            float4 w = ld4(&sm[DW_HH + d * HDIM + (ks - 8) * 64 + k]);
            acc[d] += h0*w.x + h1*w.y + h2*w.z + h3*w.w;
          }
        }
      }
#pragma unroll
      for (int d = 0; d < 8; ++d) sm[DSCR + (d * 64 + b) * 17 + ks] = acc[d];
      __syncthreads();
      if (tid < 512) {
        const int dd = tid >> 6, bb = tid & 63;
        float s16 = 0.f;
#pragma unroll
        for (int i = 0; i < 16; ++i) s16 += sm[DSCR + (dd * 64 + bb) * 17 + i];
        sm[DGL + dd * 64 + bb] = s16 + sm[DBIAS + dd];
      }
      __syncthreads();
      if (tid < 128) {
        const int bb = tid & 63, cl = tid >> 6;
        float gi = sm[DGL + (0 + cl) * 64 + bb];
        float gf = sm[DGL + (2 + cl) * 64 + bb];
        float gg = sm[DGL + (4 + cl) * 64 + bb];
        float go = sm[DGL + (6 + cl) * 64 + bb];
        float cn = sigm(gf) * c + sigm(gi) * tanhf(gg);
        float hn = sigm(go) * tanhf(cn);
        c = cn;
        AS(&hstep[(size_t)s * HB + (size_t)(j0 + cl) * BATCH + bb], hn);
      }
    }
    flag_barrier<256>(flags, release, ++ep, bid);
  }

  // ---- final prediction row (srow = 23) from hstep[NAHEAD-1] ----
  {
    const float* h_fin = hstep + (size_t)(NAHEAD - 1) * HB;
    const int ts = tid >> 6;
    float p0 = 0.f, p1 = 0.f;
    const float* w0 = w_fc + (size_t)j0 * HDIM + ts * 32;
    const float* w1 = w0 + HDIM;
    const float* hr = h_fin + (size_t)(ts * 32) * BATCH + b;
#pragma unroll 2
    for (int k = 0; k < 32; k += 4) {
      float4 wa = ld4(w0 + k), wb = ld4(w1 + k);
      float h0 = hr[(k + 0) * BATCH], h1 = hr[(k + 1) * BATCH];
      float h2 = hr[(k + 2) * BATCH], h3 = hr[(k + 3) * BATCH];
      p0 += wa.x*h0 + wa.y*h1 + wa.z*h2 + wa.w*h3;
      p1 += wb.x*h0 + wb.y*h1 + wb.z*h2 + wb.w*h3;
    }
    __syncthreads();
    sm[DRED + ts * 64 + b] = p0;
    sm[DRED + (16 + ts) * 64 + b] = p1;
    __syncthreads();
    if (tid < 128) {
      const int cl = tid >> 6;
      const int cc = j0 + cl;
      float p = 0.f;
#pragma unroll
      for (int i = 0; i < 16; ++i) p += sm[DRED + (cl * 16 + i) * 64 + b];
      out[((size_t)b * NAHEAD + (NAHEAD - 1)) * HDIM + cc] = p + b_fc[cc];
    }
  }
}

// ---------------------------------------------------------------------------
// Original global-weight cell (kept for fallback paths).
// ---------------------------------------------------------------------------
template <int DIN0>
__device__ __forceinline__ void cell_tile2(
    int j0, const float* __restrict__ in0,
    const float* __restrict__ h_in,
    const float* __restrict__ w_ih,
    const float* __restrict__ w_hh,
    const float* __restrict__ b_ih, const float* __restrict__ b_hh,
    float* __restrict__ c_state,
    float* __restrict__ h_out,
    float* __restrict__ sm)
{
  const int tid = threadIdx.x;
  const int b  = tid & 63;
  const int ks = tid >> 6;
  constexpr int K  = DIN0 + HDIM;
  constexpr int KS = K / 16;
  const int k0 = ks * KS, k1 = k0 + KS;
  const int a0 = (k0 < DIN0) ? k0 : DIN0;
  const int a1 = (k1 < DIN0) ? k1 : DIN0;
  const int c0 = (k0 > DIN0) ? k0 - DIN0 : 0;
  const int c1 = (k1 > DIN0) ? k1 - DIN0 : 0;

  const float* wi = w_ih + (size_t)j0 * DIN0;
  const float* wh = w_hh + (size_t)j0 * HDIM;

  float acc[8] = {0.f, 0.f, 0.f, 0.f, 0.f, 0.f, 0.f, 0.f};

#pragma unroll 2
  for (int k = a0; k < a1; k += 4) {
    float x0 = in0[(k + 0) * BATCH + b];
    float x1 = in0[(k + 1) * BATCH + b];
    float x2 = in0[(k + 2) * BATCH + b];
    float x3 = in0[(k + 3) * BATCH + b];
#pragma unroll
    for (int d = 0; d < 8; ++d) {
      float4 w = ld4(wi + (size_t)((d >> 1) * HDIM + (d & 1)) * DIN0 + k);
      acc[d] += x0 * w.x + x1 * w.y + x2 * w.z + x3 * w.w;
    }
  }
#pragma unroll 2
  for (int k = c0; k < c1; k += 4) {
    float h0 = h_in[(k + 0) * BATCH + b];
    float h1 = h_in[(k + 1) * BATCH + b];
    float h2 = h_in[(k + 2) * BATCH + b];
    float h3 = h_in[(k + 3) * BATCH + b];
#pragma unroll
    for (int d = 0; d < 8; ++d) {
      float4 w = ld4(wh + (size_t)((d >> 1) * HDIM + (d & 1)) * HDIM + k);
      acc[d] += h0 * w.x + h1 * w.y + h2 * w.z + h3 * w.w;
    }
  }

  float* gl = sm + 8 * 64 * 17;
#pragma unroll
  for (int d = 0; d < 8; ++d) sm[(d * 64 + b) * 17 + ks] = acc[d];
  __syncthreads();

  if (tid < 512) {
    const int dd = tid >> 6, bb = tid & 63;
    float s = 0.f;
#pragma unroll
    for (int i = 0; i < 16; ++i) s += sm[(dd * 64 + bb) * 17 + i];
    const int r = (dd >> 1) * HDIM + j0 + (dd & 1);
    gl[dd * 64 + bb] = s + b_ih[r] + b_hh[r];
  }
  __syncthreads();

  if (tid < 128) {
    const int bb = tid & 63, cl = tid >> 6;
    const int jc = j0 + cl;
    float gi = gl[(0 + cl) * 64 + bb];
    float gf = gl[(2 + cl) * 64 + bb];
    float gg = gl[(4 + cl) * 64 + bb];
    float go = gl[(6 + cl) * 64 + bb];
    float cold = c_state[(size_t)jc * BATCH + bb];
    float cn = sigm(gf) * cold + sigm(gi) * tanhf(gg);
    float hn = sigm(go) * tanhf(cn);
    c_state[(size_t)jc * BATCH + bb] = cn;
    h_out[(size_t)jc * BATCH + bb] = hn;
  }
  __syncthreads();
}

__global__ __launch_bounds__(1024, 1)
void lstm_step(int t,
               const float* __restrict__ xT,
               const float* __restrict__ w_ih0, const float* __restrict__ w_hh0,
               const float* __restrict__ b_ih0, const float* __restrict__ b_hh0,
               const float* __restrict__ w_ih1, const float* __restrict__ w_hh1,
               const float* __restrict__ b_ih1, const float* __restrict__ b_hh1,
               float* __restrict__ seq0, float* __restrict__ enc,
               float* __restrict__ cst0, float* __restrict__ cst1)
{
  __shared__ float sm[8 * 64 * 17 + 8 * 64];
  const int j0 = blockIdx.x * 2;
  if (t < TT)
    cell_tile2<IDIM>(j0, xT + (size_t)t * IDIM * BATCH,
                     seq0 + (size_t)t * HB,
                     w_ih0, w_hh0, b_ih0, b_hh0,
                     cst0, seq0 + (size_t)(t + 1) * HB, sm);
  if (t >= 1)
    cell_tile2<HDIM>(j0, seq0 + (size_t)t * HB,
                     enc + (size_t)(t - 1) * HB,
                     w_ih1, w_hh1, b_ih1, b_hh1,
                     cst1, enc + (size_t)t * HB, sm);
}

__global__ __launch_bounds__(1024, 1)
void dec_gates(const float* __restrict__ xi, const float* __restrict__ h_cur,
               const float* __restrict__ w_ih, const float* __restrict__ w_hh,
               const float* __restrict__ b_ih, const float* __restrict__ b_hh,
               float* __restrict__ cst, float* __restrict__ h_out)
{
  __shared__ float sm[8 * 64 * 17 + 8 * 64];
  cell_tile2<HDIM>(blockIdx.x * 2, xi, h_cur, w_ih, w_hh, b_ih, b_hh,
                   cst, h_out, sm);
}

__global__ __launch_bounds__(512, 2)
void attn_scores(const float* __restrict__ enc,
                 const float* __restrict__ h_cur,
                 float* __restrict__ scores)
{
  __shared__ float red[2][8][64];
  const int tid = threadIdx.x;
  const int b  = tid & 63;
  const int ks = tid >> 6;
  const int t0 = blockIdx.x * 2;
  const float* e0 = enc + (size_t)(t0 + 1) * HB + ks * 64 * BATCH;
  const float* e1 = e0 + HB;
  const float* hr = h_cur + ks * 64 * BATCH;
  float a0 = 0.f, a1 = 0.f;
#pragma unroll 4
  for (int k = 0; k < 64; ++k) {
    float hv = hr[k * BATCH + b];
    a0 += hv * e0[k * BATCH + b];
    a1 += hv * e1[k * BATCH + b];
  }
  red[0][ks][b] = a0;
  red[1][ks][b] = a1;
  __syncthreads();
  if (tid < 128) {
    int tl = tid >> 6;
    float s = 0.f;
#pragma unroll
    for (int i = 0; i < 8; ++i) s += red[tl][i][b];
    scores[(size_t)(t0 + tl) * BATCH + b] = s;
  }
}

__global__ __launch_bounds__(512, 2)
void attn_ctx(const float* __restrict__ enc,
              const float* __restrict__ scores,
              const float* __restrict__ h_cur,
              const float* __restrict__ w_fc, const float* __restrict__ b_fc,
              float* __restrict__ xi,
              float* __restrict__ out,
              int s)
{
  __shared__ float red[8][2][64];
  __shared__ float mz[2][64];
  __shared__ float ctxv[2][64];
  const int tid = threadIdx.x;
  const int b  = tid & 63;
  const int ts = tid >> 6;
  const int hc0 = blockIdx.x * 2;

  float m = -1e30f;
  for (int t = ts * 64; t < ts * 64 + 64; ++t)
    m = fmaxf(m, scores[(size_t)t * BATCH + b]);
  red[ts][0][b] = m;
  __syncthreads();
  if (tid < 64) {
    float mm = red[0][0][b];
#pragma unroll
    for (int i = 1; i < 8; ++i) mm = fmaxf(mm, red[i][0][b]);
    mz[0][b] = mm;
  }
  __syncthreads();
  m = mz[0][b];
  float z = 0.f;
  for (int t = ts * 64; t < ts * 64 + 64; ++t)
    z += expf(scores[(size_t)t * BATCH + b] - m);
  red[ts][1][b] = z;
  __syncthreads();
  if (tid < 64) {
    float zz = 0.f;
#pragma unroll
    for (int i = 0; i < 8; ++i) zz += red[i][1][b];
    mz[1][b] = 1.f / zz;
  }
  __syncthreads();
  const float rZ = mz[1][b];

  float a0 = 0.f, a1 = 0.f;
  const float* eb = enc + HB + (size_t)hc0 * BATCH + b;
  for (int t = ts * 64; t < ts * 64 + 64; ++t) {
    float p = expf(scores[(size_t)t * BATCH + b] - m) * rZ;
    a0 += p * eb[(size_t)t * HB];
    a1 += p * eb[(size_t)t * HB + BATCH];
  }
  __syncthreads();
  red[ts][0][b] = a0;
  red[ts][1][b] = a1;
  __syncthreads();
  if (tid < 128) {
    int cl = tid >> 6;
    float c = 0.f;
#pragma unroll
    for (int i = 0; i < 8; ++i) c += red[i][cl][b];
    ctxv[cl][b] = c;
  }

  float p0 = 0.f, p1 = 0.f;
  if (s >= 1) {
    const float* w0 = w_fc + (size_t)hc0 * HDIM + ts * 64;
    const float* w1 = w0 + HDIM;
    const float* hr = h_cur + ts * 64 * BATCH;
#pragma unroll 2
    for (int k = 0; k < 64; k += 4) {
      float4 wa = ld4(w0 + k), wb = ld4(w1 + k);
      float h0 = hr[(k + 0) * BATCH + b], h1 = hr[(k + 1) * BATCH + b];
      float h2 = hr[(k + 2) * BATCH + b], h3 = hr[(k + 3) * BATCH + b];
      p0 += wa.x * h0 + wa.y * h1 + wa.z * h2 + wa.w * h3;
      p1 += wb.x * h0 + wb.y * h1 + wb.z * h2 + wb.w * h3;
    }
  }
  __syncthreads();
  red[ts][0][b] = p0;
  red[ts][1][b] = p1;
  __syncthreads();
  if (tid < 128) {
    int cl = tid >> 6;
    int cc = hc0 + cl;
    float pred = 0.f;
    if (s >= 1) {
#pragma unroll
      for (int i = 0; i < 8; ++i) pred += red[i][cl][b];
      pred += b_fc[cc];
      out[((size_t)b * NAHEAD + (s - 1)) * HDIM + cc] = pred;
    }
    xi[(size_t)cc * BATCH + b] = ctxv[cl][b] + pred;
  }
}

__global__ __launch_bounds__(512, 2)
void fc_out(const float* __restrict__ h, const float* __restrict__ w_fc,
            const float* __restrict__ b_fc, float* __restrict__ out, int srow)
{
  __shared__ float red[8][2][64];
  const int tid = threadIdx.x;
  const int b  = tid & 63;
  const int ks = tid >> 6;
  const int cc0 = blockIdx.x * 2;
  const float* w0 = w_fc + (size_t)cc0 * HDIM + ks * 64;
  const float* w1 = w0 + HDIM;
  const float* hr = h + ks * 64 * BATCH;
  float p0 = 0.f, p1 = 0.f;
#pragma unroll 2
  for (int k = 0; k < 64; k += 4) {
    float4 wa = ld4(w0 + k), wb = ld4(w1 + k);
    float h0 = hr[(k + 0) * BATCH + b], h1 = hr[(k + 1) * BATCH + b];
    float h2 = hr[(k + 2) * BATCH + b], h3 = hr[(k + 3) * BATCH + b];
    p0 += wa.x * h0 + wa.y * h1 + wa.z * h2 + wa.w * h3;
    p1 += wb.x * h0 + wb.y * h1 + wb.z * h2 + wb.w * h3;
  }
  red[ks][0][b] = p0;
  red[ks][1][b] = p1;
  __syncthreads();
  if (tid < 128) {
    int cl = tid >> 6;
    int cc = cc0 + cl;
    float p = 0.f;
#pragma unroll
    for (int i = 0; i < 8; ++i) p += red[i][cl][b];
    out[((size_t)b * NAHEAD + srow) * HDIM + cc] = p + b_fc[cc];
  }
}

__global__ __launch_bounds__(256)
void transpose_x(const float* __restrict__ x, float* __restrict__ xT)
{
  __shared__ float tile[64][65];
  const int t = blockIdx.x;
  const int lane = threadIdx.x & 63;
  const int w    = threadIdx.x >> 6;
#pragma unroll
  for (int ii = 0; ii < 16; ++ii) {
    int b = w * 16 + ii;
    tile[b][lane] = x[((size_t)b * TT + t) * IDIM + lane];
  }
  __syncthreads();
#pragma unroll
  for (int ii = 0; ii < 16; ++ii) {
    int i = w * 16 + ii;
    xT[((size_t)t * IDIM + i) * BATCH + lane] = tile[lane][i];
  }
}

// ---------------------------------------------------------------------------
extern "C" void kernel_launch(void* const* d_in, const int* in_sizes, int n_in,
                              void* d_out, int out_size, void* d_ws, size_t ws_size,
                              hipStream_t stream) {
  const float* x     = (const float*)d_in[0];
  const float* w_ih0 = (const float*)d_in[1];
  const float* w_hh0 = (const float*)d_in[2];
  const float* b_ih0 = (const float*)d_in[3];
  const float* b_hh0 = (const float*)d_in[4];
  const float* w_ih1 = (const float*)d_in[5];
  const float* w_hh1 = (const float*)d_in[6];
  const float* b_ih1 = (const float*)d_in[7];
  const float* b_hh1 = (const float*)d_in[8];
  const float* w_ihd = (const float*)d_in[9];
  const float* w_hhd = (const float*)d_in[10];
  const float* b_ihd = (const float*)d_in[11];
  const float* b_hhd = (const float*)d_in[12];
  const float* w_fc  = (const float*)d_in[13];
  const float* b_fc  = (const float*)d_in[14];
  float* out = (float*)d_out;

  char* ws = (char*)d_ws;
  size_t off = 0;
  auto alloc = [&](size_t bytes) -> void* {
    void* p = ws + off;
    off += (bytes + 255) & ~(size_t)255;
    return p;
  };

  float* cst0 = (float*)alloc((size_t)HB * 4);            // zero (fallback)
  float* cst1 = (float*)alloc((size_t)HB * 4);            // final L1 c-state
  float* seq0 = (float*)alloc((size_t)(TT + 1) * HB * 4); // slot0 zero
  float* enc  = (float*)alloc((size_t)(TT + 1) * HB * 4); // slot0 zero
  float* xT   = (float*)alloc((size_t)TT * IDIM * BATCH * 4);
  float* scores = (float*)alloc((size_t)NAHEAD * TT * BATCH * 4); // per-step
  float* xi     = (float*)alloc((size_t)NAHEAD * HB * 4);         // per-step
  float* hstep  = (float*)alloc((size_t)NAHEAD * HB * 4);         // per-step
  unsigned* flags    = (unsigned*)alloc(512 * 16 * 4);    // encoder barrier
  unsigned* release  = (unsigned*)alloc(256);
  unsigned* flags2   = (unsigned*)alloc(256 * 16 * 4);    // decoder barrier
  unsigned* release2 = (unsigned*)alloc(256);
  (void)ws_size; (void)in_sizes; (void)n_in; (void)out_size;

  hipMemsetAsync(cst0, 0, (size_t)HB * 4 * 2, stream);    // cst0+cst1
  hipMemsetAsync(seq0, 0, (size_t)HB * 4, stream);
  hipMemsetAsync(enc,  0, (size_t)HB * 4, stream);
  hipMemsetAsync(flags, 0, 512 * 16 * 4, stream);
  hipMemsetAsync(release, 0, 256, stream);
  hipMemsetAsync(flags2, 0, 256 * 16 * 4, stream);
  hipMemsetAsync(release2, 0, 256, stream);

  transpose_x<<<TT, 256, 0, stream>>>(x, xT);

  static bool attr_set = false;
  if (!attr_set) {
    hipFuncSetAttribute(reinterpret_cast<const void*>(encoder_coop),
                        hipFuncAttributeMaxDynamicSharedMemorySize,
                        ENC_SMEM_BYTES);
    hipFuncSetAttribute(reinterpret_cast<const void*>(decoder_coop),
                        hipFuncAttributeMaxDynamicSharedMemorySize,
                        DEC_SMEM_BYTES);
    attr_set = true;
  }

  // ---- encoder: ONE cooperative kernel, 512 WGs (2/CU, 32 waves/CU) ----
  void* args[] = {
    (void*)&xT,
    (void*)&w_ih0, (void*)&w_hh0, (void*)&b_ih0, (void*)&b_hh0,
    (void*)&w_ih1, (void*)&w_hh1, (void*)&b_ih1, (void*)&b_hh1,
    (void*)&seq0, (void*)&enc, (void*)&cst1, (void*)&flags, (void*)&release
  };
  hipError_t cerr = hipLaunchCooperativeKernel(
      reinterpret_cast<void*>(encoder_coop), dim3(512), dim3(1024),
      args, (unsigned)ENC_SMEM_BYTES, stream);
  if (cerr != hipSuccess) {
    for (int t = 0; t <= TT; ++t) {
      lstm_step<<<256, 1024, 0, stream>>>(
          t, xT, w_ih0, w_hh0, b_ih0, b_hh0,
          w_ih1, w_hh1, b_ih1, b_hh1, seq0, enc, cst0, cst1);
    }
  }

  // ---- decoder: ONE cooperative kernel, step-indexed buffers ----
  void* dargs[] = {
    (void*)&enc, (void*)&w_ihd, (void*)&w_hhd, (void*)&b_ihd, (void*)&b_hhd,
    (void*)&w_fc, (void*)&b_fc, (void*)&cst1,
    (void*)&scores, (void*)&xi, (void*)&hstep, (void*)&out,
    (void*)&flags2, (void*)&release2
  };
  hipError_t derr = hipLaunchCooperativeKernel(
      reinterpret_cast<void*>(decoder_coop), dim3(256), dim3(1024),
      dargs, (unsigned)DEC_SMEM_BYTES, stream);
  if (derr != hipSuccess) {
    // fallback: launch-based decoder reusing slot 0 / slots 0,1
    const float* h_cur = enc + (size_t)TT * HB;
    for (int s = 0; s < NAHEAD; ++s) {
      attn_scores<<<256, 512, 0, stream>>>(enc, h_cur, scores);
      attn_ctx<<<256, 512, 0, stream>>>(enc, scores, h_cur, w_fc, b_fc,
                                        xi, out, s);
      float* h_nxt = hstep + (size_t)(s & 1) * HB;
      dec_gates<<<256, 1024, 0, stream>>>(xi, h_cur, w_ihd, w_hhd,
                                          b_ihd, b_hhd, cst1, h_nxt);
      h_cur = h_nxt;
    }
    fc_out<<<256, 512, 0, stream>>>(h_cur, w_fc, b_fc, out, NAHEAD - 1);
  }
}

// Round 12
// 7245.678 us; speedup vs baseline: 3.4926x; 2.1455x over previous
//
#include <hip/hip_runtime.h>

#define BATCH  64
#define TT     512
#define IDIM   64
#define HDIM   512
#define NAHEAD 24
#define HB     (HDIM * BATCH)

// ---- encoder_coop LDS layout (float offsets into extern smem[]) ----
// THE stable operating point (verified rounds 6/8/9: VGPR 64, zero spill,
// encoder 6.3-6.6 ms). Deviations all spilled catastrophically:
//   r4  monolithic 64-reg stage  -> 42 GB scratch traffic
//   r7  r=4 batch quads          -> 250 GB
//   r10 global-weight burns      -> 45 GB
//   r11 launch_bounds(1024,8)    -> VGPR forced to 32, 39 GB
#define WIH0_OFF   0                            // 8*64   = 512
#define WHH0_OFF   512                          // 8*512  = 4096
#define WIH1_OFF   4608
#define WHH1_OFF   8704
#define SCR_OFF    12800                        // 16*64*17 = 17408
#define GL_OFF     30208                        // 16*64    = 1024
#define BIAS_OFF   31232                        // 16
#define ENC_SMEM_FLOATS 31248
#define ENC_SMEM_BYTES  (ENC_SMEM_FLOATS * 4)   // 124992 B < 160 KiB

typedef float v2f __attribute__((ext_vector_type(2)));

__device__ __forceinline__ float4 ld4(const float* p) {
  return *reinterpret_cast<const float4*>(p);
}
__device__ __forceinline__ float sigm(float x) { return 1.0f / (1.0f + expf(-x)); }

// Agent-scope write-through store for cross-WG data (readers on other XCDs;
// per-XCD L2s not coherent). Agent-scope LOADS bypass local L2 (~2x cost,
// round-8) — cross-step data is write-once and read with plain cached loads.
__device__ __forceinline__ void AS(float* p, float v) {
  __hip_atomic_store(p, v, __ATOMIC_RELAXED, __HIP_MEMORY_SCOPE_AGENT);
}

// ---------------------------------------------------------------------------
// Flag-array grid barrier (flush-free, RMW-free arrivals). No cache
// maintenance (cg::grid.sync's per-step L2 flush was the round-1 regression).
// Cross-step data is agent-scope stored + vmcnt-drained before the flag
// store, and only read next epoch — no stale L2 copy can exist.
// ---------------------------------------------------------------------------
__device__ __forceinline__ void flag_barrier(unsigned* flags, unsigned* release,
                                             unsigned epoch, int bid) {
  asm volatile("s_waitcnt vmcnt(0)" ::: "memory");
  __syncthreads();
  if (threadIdx.x == 0)
    __hip_atomic_store(&flags[(size_t)bid * 16], epoch,
                       __ATOMIC_RELAXED, __HIP_MEMORY_SCOPE_AGENT);
  asm volatile("" ::: "memory");
  if (bid == 0 && threadIdx.x < 64) {
    const int l = threadIdx.x;
    for (;;) {
      bool ok = true;
#pragma unroll
      for (int i = 0; i < 4; ++i) {
        unsigned v = __hip_atomic_load(&flags[(size_t)(l * 4 + i) * 16],
                                       __ATOMIC_RELAXED, __HIP_MEMORY_SCOPE_AGENT);
        ok &= (v >= epoch);
      }
      if (__all(ok)) break;
      __builtin_amdgcn_s_sleep(1);
    }
    if (threadIdx.x == 0)
      __hip_atomic_store(release, epoch, __ATOMIC_RELAXED,
                         __HIP_MEMORY_SCOPE_AGENT);
  }
  if (threadIdx.x == 0) {
    while (__hip_atomic_load(release, __ATOMIC_RELAXED,
                             __HIP_MEMORY_SCOPE_AGENT) < epoch)
      __builtin_amdgcn_s_sleep(1);
  }
  __syncthreads();
  asm volatile("" ::: "memory");
}

// Stage 8 k-elements for 2 batches (bp, bp+32) as v2f; static indices only.
#define STG8(dst, base, off0)                                          \
  _Pragma("unroll") for (int i = 0; i < 8; ++i) {                      \
    dst[i].x = (base)[((off0) + i) * BATCH];                           \
    dst[i].y = (base)[((off0) + i) * BATCH + 32];                      \
  }

#define BURN_S(sarr, C0)                                                      \
  do {                                                                        \
    _Pragma("unroll") for (int c = 0; c < 8; c += 4) {                        \
      if (t < TT) {                                                           \
        _Pragma("unroll") for (int d = 0; d < 8; ++d) {                       \
          float4 w = ld4(&smem[WHH0_OFF + d * HDIM + ks * 16 + (C0) + c]);    \
          a0[d] += sarr[c]*w.x + sarr[c+1]*w.y + sarr[c+2]*w.z + sarr[c+3]*w.w;\
        }                                                                     \
      }                                                                       \
      if (t >= 1) {                                                           \
        _Pragma("unroll") for (int d = 0; d < 8; ++d) {                       \
          float4 w = ld4(&smem[WIH1_OFF + d * HDIM + ks * 16 + (C0) + c]);    \
          a1[d] += sarr[c]*w.x + sarr[c+1]*w.y + sarr[c+2]*w.z + sarr[c+3]*w.w;\
        }                                                                     \
      }                                                                       \
    }                                                                         \
  } while (0)

#define BURN_E(earr, C0)                                                      \
  do {                                                                        \
    if (t >= 1) {                                                             \
      _Pragma("unroll") for (int c = 0; c < 8; c += 4) {                      \
        _Pragma("unroll") for (int d = 0; d < 8; ++d) {                       \
          float4 w = ld4(&smem[WHH1_OFF + d * HDIM + ks * 16 + (C0) + c]);    \
          a1[d] += earr[c]*w.x + earr[c+1]*w.y + earr[c+2]*w.z + earr[c+3]*w.w;\
        }                                                                     \
      }                                                                       \
    }                                                                         \
  } while (0)

// ---------------------------------------------------------------------------
// Merged-cell encoder (round-6/9 verified): 256 WGs x 1024 (1 WG/CU),
// r=2 batch pairs, LDS weights, shfl merge, stride-17 scratch, 1 barrier/step.
// ---------------------------------------------------------------------------
__global__ __launch_bounds__(1024, 4)
void encoder_coop(const float* __restrict__ xT,
                  const float* __restrict__ w_ih0, const float* __restrict__ w_hh0,
                  const float* __restrict__ b_ih0, const float* __restrict__ b_hh0,
                  const float* __restrict__ w_ih1, const float* __restrict__ w_hh1,
                  const float* __restrict__ b_ih1, const float* __restrict__ b_hh1,
                  float* __restrict__ seq0,        // [T+1][H][B], slot0 zero
                  float* __restrict__ enc,         // [T+1][H][B], slot0 zero
                  float* __restrict__ cst1,        // [H][B] final L1 c-state
                  unsigned* flags, unsigned* release)
{
  extern __shared__ float smem[];
  const int tid  = threadIdx.x;
  const int bid  = blockIdx.x;
  const int j0   = bid * 2;
  const int lane = tid & 63;
  const int wv   = tid >> 6;                     // 0..15 (scratch slot)
  const int bp   = tid & 31;                     // batch pair {bp, bp+32}
  const int ks   = tid >> 5;                     // 0..31 (k-slice of 16)

  for (int idx = tid; idx < 8 * IDIM; idx += 1024) {
    int d = idx >> 6, k = idx & 63;
    size_t r = (size_t)((d >> 1) * HDIM + j0 + (d & 1));
    smem[WIH0_OFF + idx] = w_ih0[r * IDIM + k];
  }
  for (int idx = tid; idx < 8 * HDIM; idx += 1024) {
    int d = idx >> 9, k = idx & 511;
    size_t r = (size_t)((d >> 1) * HDIM + j0 + (d & 1));
    smem[WHH0_OFF + idx] = w_hh0[r * HDIM + k];
    smem[WIH1_OFF + idx] = w_ih1[r * HDIM + k];
    smem[WHH1_OFF + idx] = w_hh1[r * HDIM + k];
  }
  if (tid < 16) {
    int d = tid & 7;
    size_t r = (size_t)((d >> 1) * HDIM + j0 + (d & 1));
    smem[BIAS_OFF + tid] = (tid < 8) ? (b_ih0[r] + b_hh0[r])
                                     : (b_ih1[r] + b_hh1[r]);
  }
  __syncthreads();

  float c0 = 0.f;                                // valid for tid < 128
  float c1 = 0.f;                                // valid for 128 <= tid < 256

  for (int t = 0; t <= TT; ++t) {
    const float* sp = seq0 + (size_t)t * HB + (size_t)(ks * 16) * BATCH + bp;
    const float* ep = enc + (size_t)(t >= 1 ? t - 1 : 0) * HB
                          + (size_t)(ks * 16) * BATCH + bp;

    v2f sA[8], sB[8], eA[8], eB[8];
    v2f xv[4];

    STG8(sA, sp, 0);
    STG8(sB, sp, 8);
    if (t < TT && ks < 16) {
      const float* xp = xT + (size_t)t * IDIM * BATCH
                           + (size_t)(ks * 4) * BATCH + bp;
#pragma unroll
      for (int i = 0; i < 4; ++i) {
        xv[i].x = xp[i * BATCH];
        xv[i].y = xp[i * BATCH + 32];
      }
    }

    v2f a0[8], a1[8];
#pragma unroll
    for (int d = 0; d < 8; ++d) { a0[d] = 0.f; a1[d] = 0.f; }

    if (t < TT && ks < 16) {
#pragma unroll
      for (int d = 0; d < 8; ++d) {
        float4 w = ld4(&smem[WIH0_OFF + d * IDIM + ks * 4]);
        a0[d] += xv[0]*w.x + xv[1]*w.y + xv[2]*w.z + xv[3]*w.w;
      }
    }

    BURN_S(sA, 0);
    if (t >= 1) STG8(eA, ep, 0);
    BURN_S(sB, 8);
    if (t >= 1) STG8(eB, ep, 8);
    BURN_E(eA, 0);
    BURN_E(eB, 8);

#pragma unroll
    for (int d = 0; d < 8; ++d) {
      float m0x = a0[d].x + __shfl_xor(a0[d].x, 32);
      float m0y = a0[d].y + __shfl_xor(a0[d].y, 32);
      smem[SCR_OFF + (d * 64 + lane) * 17 + wv] = (lane >= 32) ? m0y : m0x;
      float m1x = a1[d].x + __shfl_xor(a1[d].x, 32);
      float m1y = a1[d].y + __shfl_xor(a1[d].y, 32);
      smem[SCR_OFF + ((8 + d) * 64 + lane) * 17 + wv] = (lane >= 32) ? m1y : m1x;
    }
    __syncthreads();

    {
      const int dd = tid >> 6, bb = tid & 63;
      float s = 0.f;
#pragma unroll
      for (int i = 0; i < 16; ++i) s += smem[SCR_OFF + (dd * 64 + bb) * 17 + i];
      smem[GL_OFF + dd * 64 + bb] = s + smem[BIAS_OFF + dd];
    }
    __syncthreads();

    if (tid < 256) {
      const int bb = tid & 63, u = tid >> 6;
      if (u < 2) {
        if (t < TT) {
          const int cl = u;
          float gi = smem[GL_OFF + (0 + cl) * 64 + bb];
          float gf = smem[GL_OFF + (2 + cl) * 64 + bb];
          float gg = smem[GL_OFF + (4 + cl) * 64 + bb];
          float go = smem[GL_OFF + (6 + cl) * 64 + bb];
          float cn = sigm(gf) * c0 + sigm(gi) * tanhf(gg);
          float hn = sigm(go) * tanhf(cn);
          c0 = cn;
          AS(&seq0[(size_t)(t + 1) * HB + (size_t)(j0 + cl) * BATCH + bb], hn);
        }
      } else {
        if (t >= 1) {
          const int cl = u - 2;
          float gi = smem[GL_OFF + (8 + 0 + cl) * 64 + bb];
          float gf = smem[GL_OFF + (8 + 2 + cl) * 64 + bb];
          float gg = smem[GL_OFF + (8 + 4 + cl) * 64 + bb];
          float go = smem[GL_OFF + (8 + 6 + cl) * 64 + bb];
          float cn = sigm(gf) * c1 + sigm(gi) * tanhf(gg);
          float hn = sigm(go) * tanhf(cn);
          c1 = cn;
          AS(&enc[(size_t)t * HB + (size_t)(j0 + cl) * BATCH + bb], hn);
        }
      }
    }

    if (t < TT) flag_barrier(flags, release, (unsigned)(t + 1), bid);
  }

  if (tid >= 128 && tid < 256)
    cst1[(size_t)(j0 + ((tid >> 6) - 2)) * BATCH + (tid & 63)] = c1;
}

// ---------------------------------------------------------------------------
// Global-weight LSTM cell (decoder gates + encoder fallback).
// ---------------------------------------------------------------------------
template <int DIN0>
__device__ __forceinline__ void cell_tile2(
    int j0, const float* __restrict__ in0,
    const float* __restrict__ h_in,
    const float* __restrict__ w_ih,
    const float* __restrict__ w_hh,
    const float* __restrict__ b_ih, const float* __restrict__ b_hh,
    float* __restrict__ c_state,
    float* __restrict__ h_out,
    float* __restrict__ sm)
{
  const int tid = threadIdx.x;
  const int b  = tid & 63;
  const int ks = tid >> 6;
  constexpr int K  = DIN0 + HDIM;
  constexpr int KS = K / 16;
  const int k0 = ks * KS, k1 = k0 + KS;
  const int a0 = (k0 < DIN0) ? k0 : DIN0;
  const int a1 = (k1 < DIN0) ? k1 : DIN0;
  const int c0 = (k0 > DIN0) ? k0 - DIN0 : 0;
  const int c1 = (k1 > DIN0) ? k1 - DIN0 : 0;

  const float* wi = w_ih + (size_t)j0 * DIN0;
  const float* wh = w_hh + (size_t)j0 * HDIM;

  float acc[8] = {0.f, 0.f, 0.f, 0.f, 0.f, 0.f, 0.f, 0.f};

#pragma unroll 2
  for (int k = a0; k < a1; k += 4) {
    float x0 = in0[(k + 0) * BATCH + b];
    float x1 = in0[(k + 1) * BATCH + b];
    float x2 = in0[(k + 2) * BATCH + b];
    float x3 = in0[(k + 3) * BATCH + b];
#pragma unroll
    for (int d = 0; d < 8; ++d) {
      float4 w = ld4(wi + (size_t)((d >> 1) * HDIM + (d & 1)) * DIN0 + k);
      acc[d] += x0 * w.x + x1 * w.y + x2 * w.z + x3 * w.w;
    }
  }
#pragma unroll 2
  for (int k = c0; k < c1; k += 4) {
    float h0 = h_in[(k + 0) * BATCH + b];
    float h1 = h_in[(k + 1) * BATCH + b];
    float h2 = h_in[(k + 2) * BATCH + b];
    float h3 = h_in[(k + 3) * BATCH + b];
#pragma unroll
    for (int d = 0; d < 8; ++d) {
      float4 w = ld4(wh + (size_t)((d >> 1) * HDIM + (d & 1)) * HDIM + k);
      acc[d] += h0 * w.x + h1 * w.y + h2 * w.z + h3 * w.w;
    }
  }

  float* gl = sm + 8 * 64 * 17;
#pragma unroll
  for (int d = 0; d < 8; ++d) sm[(d * 64 + b) * 17 + ks] = acc[d];
  __syncthreads();

  if (tid < 512) {
    const int dd = tid >> 6, bb = tid & 63;
    float s = 0.f;
#pragma unroll
    for (int i = 0; i < 16; ++i) s += sm[(dd * 64 + bb) * 17 + i];
    const int r = (dd >> 1) * HDIM + j0 + (dd & 1);
    gl[dd * 64 + bb] = s + b_ih[r] + b_hh[r];
  }
  __syncthreads();

  if (tid < 128) {
    const int bb = tid & 63, cl = tid >> 6;
    const int jc = j0 + cl;
    float gi = gl[(0 + cl) * 64 + bb];
    float gf = gl[(2 + cl) * 64 + bb];
    float gg = gl[(4 + cl) * 64 + bb];
    float go = gl[(6 + cl) * 64 + bb];
    float cold = c_state[(size_t)jc * BATCH + bb];
    float cn = sigm(gf) * cold + sigm(gi) * tanhf(gg);
    float hn = sigm(go) * tanhf(cn);
    c_state[(size_t)jc * BATCH + bb] = cn;
    h_out[(size_t)jc * BATCH + bb] = hn;
  }
  __syncthreads();
}

// Fallback per-step kernel (only used if cooperative launch fails).
__global__ __launch_bounds__(1024, 1)
void lstm_step(int t,
               const float* __restrict__ xT,
               const float* __restrict__ w_ih0, const float* __restrict__ w_hh0,
               const float* __restrict__ b_ih0, const float* __restrict__ b_hh0,
               const float* __restrict__ w_ih1, const float* __restrict__ w_hh1,
               const float* __restrict__ b_ih1, const float* __restrict__ b_hh1,
               float* __restrict__ seq0, float* __restrict__ enc,
               float* __restrict__ cst0, float* __restrict__ cst1)
{
  __shared__ float sm[8 * 64 * 17 + 8 * 64];
  const int j0 = blockIdx.x * 2;
  if (t < TT)
    cell_tile2<IDIM>(j0, xT + (size_t)t * IDIM * BATCH,
                     seq0 + (size_t)t * HB,
                     w_ih0, w_hh0, b_ih0, b_hh0,
                     cst0, seq0 + (size_t)(t + 1) * HB, sm);
  if (t >= 1)
    cell_tile2<HDIM>(j0, seq0 + (size_t)t * HB,
                     enc + (size_t)(t - 1) * HB,
                     w_ih1, w_hh1, b_ih1, b_hh1,
                     cst1, enc + (size_t)t * HB, sm);
}

__global__ __launch_bounds__(1024, 1)
void dec_gates(const float* __restrict__ xi, const float* __restrict__ h_cur,
               const float* __restrict__ w_ih, const float* __restrict__ w_hh,
               const float* __restrict__ b_ih, const float* __restrict__ b_hh,
               float* __restrict__ cst, float* __restrict__ h_out)
{
  __shared__ float sm[8 * 64 * 17 + 8 * 64];
  cell_tile2<HDIM>(blockIdx.x * 2, xi, h_cur, w_ih, w_hh, b_ih, b_hh,
                   cst, h_out, sm);
}

__global__ __launch_bounds__(512, 2)
void attn_scores(const float* __restrict__ enc,
                 const float* __restrict__ h_cur,
                 float* __restrict__ scores)
{
  __shared__ float red[2][8][64];
  const int tid = threadIdx.x;
  const int b  = tid & 63;
  const int ks = tid >> 6;
  const int t0 = blockIdx.x * 2;
  const float* e0 = enc + (size_t)(t0 + 1) * HB + ks * 64 * BATCH;
  const float* e1 = e0 + HB;
  const float* hr = h_cur + ks * 64 * BATCH;
  float a0 = 0.f, a1 = 0.f;
#pragma unroll 4
  for (int k = 0; k < 64; ++k) {
    float hv = hr[k * BATCH + b];
    a0 += hv * e0[k * BATCH + b];
    a1 += hv * e1[k * BATCH + b];
  }
  red[0][ks][b] = a0;
  red[1][ks][b] = a1;
  __syncthreads();
  if (tid < 128) {
    int tl = tid >> 6;
    float s = 0.f;
#pragma unroll
    for (int i = 0; i < 8; ++i) s += red[tl][i][b];
    scores[(size_t)(t0 + tl) * BATCH + b] = s;
  }
}

__global__ __launch_bounds__(512, 2)
void attn_ctx(const float* __restrict__ enc,
              const float* __restrict__ scores,
              const float* __restrict__ h_cur,
              const float* __restrict__ w_fc, const float* __restrict__ b_fc,
              float* __restrict__ xi,
              float* __restrict__ out,
              int s)
{
  __shared__ float red[8][2][64];
  __shared__ float mz[2][64];
  __shared__ float ctxv[2][64];
  const int tid = threadIdx.x;
  const int b  = tid & 63;
  const int ts = tid >> 6;
  const int hc0 = blockIdx.x * 2;

  float m = -1e30f;
  for (int t = ts * 64; t < ts * 64 + 64; ++t)
    m = fmaxf(m, scores[(size_t)t * BATCH + b]);
  red[ts][0][b] = m;
  __syncthreads();
  if (tid < 64) {
    float mm = red[0][0][b];
#pragma unroll
    for (int i = 1; i < 8; ++i) mm = fmaxf(mm, red[i][0][b]);
    mz[0][b] = mm;
  }
  __syncthreads();
  m = mz[0][b];
  float z = 0.f;
  for (int t = ts * 64; t < ts * 64 + 64; ++t)
    z += expf(scores[(size_t)t * BATCH + b] - m);
  red[ts][1][b] = z;
  __syncthreads();
  if (tid < 64) {
    float zz = 0.f;
#pragma unroll
    for (int i = 0; i < 8; ++i) zz += red[i][1][b];
    mz[1][b] = 1.f / zz;
  }
  __syncthreads();
  const float rZ = mz[1][b];

  float a0 = 0.f, a1 = 0.f;
  const float* eb = enc + HB + (size_t)hc0 * BATCH + b;
  for (int t = ts * 64; t < ts * 64 + 64; ++t) {
    float p = expf(scores[(size_t)t * BATCH + b] - m) * rZ;
    a0 += p * eb[(size_t)t * HB];
    a1 += p * eb[(size_t)t * HB + BATCH];
  }
  __syncthreads();
  red[ts][0][b] = a0;
  red[ts][1][b] = a1;
  __syncthreads();
  if (tid < 128) {
    int cl = tid >> 6;
    float c = 0.f;
#pragma unroll
    for (int i = 0; i < 8; ++i) c += red[i][cl][b];
    ctxv[cl][b] = c;
  }

  float p0 = 0.f, p1 = 0.f;
  if (s >= 1) {
    const float* w0 = w_fc + (size_t)hc0 * HDIM + ts * 64;
    const float* w1 = w0 + HDIM;
    const float* hr = h_cur + ts * 64 * BATCH;
#pragma unroll 2
    for (int k = 0; k < 64; k += 4) {
      float4 wa = ld4(w0 + k), wb = ld4(w1 + k);
      float h0 = hr[(k + 0) * BATCH + b], h1 = hr[(k + 1) * BATCH + b];
      float h2 = hr[(k + 2) * BATCH + b], h3 = hr[(k + 3) * BATCH + b];
      p0 += wa.x * h0 + wa.y * h1 + wa.z * h2 + wa.w * h3;
      p1 += wb.x * h0 + wb.y * h1 + wb.z * h2 + wb.w * h3;
    }
  }
  __syncthreads();
  red[ts][0][b] = p0;
  red[ts][1][b] = p1;
  __syncthreads();
  if (tid < 128) {
    int cl = tid >> 6;
    int cc = hc0 + cl;
    float pred = 0.f;
    if (s >= 1) {
#pragma unroll
      for (int i = 0; i < 8; ++i) pred += red[i][cl][b];
      pred += b_fc[cc];
      out[((size_t)b * NAHEAD + (s - 1)) * HDIM + cc] = pred;
    }
    xi[(size_t)cc * BATCH + b] = ctxv[cl][b] + pred;
  }
}

__global__ __launch_bounds__(512, 2)
void fc_out(const float* __restrict__ h, const float* __restrict__ w_fc,
            const float* __restrict__ b_fc, float* __restrict__ out, int srow)
{
  __shared__ float red[8][2][64];
  const int tid = threadIdx.x;
  const int b  = tid & 63;
  const int ks = tid >> 6;
  const int cc0 = blockIdx.x * 2;
  const float* w0 = w_fc + (size_t)cc0 * HDIM + ks * 64;
  const float* w1 = w0 + HDIM;
  const float* hr = h + ks * 64 * BATCH;
  float p0 = 0.f, p1 = 0.f;
#pragma unroll 2
  for (int k = 0; k < 64; k += 4) {
    float4 wa = ld4(w0 + k), wb = ld4(w1 + k);
    float h0 = hr[(k + 0) * BATCH + b], h1 = hr[(k + 1) * BATCH + b];
    float h2 = hr[(k + 2) * BATCH + b], h3 = hr[(k + 3) * BATCH + b];
    p0 += wa.x * h0 + wa.y * h1 + wa.z * h2 + wa.w * h3;
    p1 += wb.x * h0 + wb.y * h1 + wb.z * h2 + wb.w * h3;
  }
  red[ks][0][b] = p0;
  red[ks][1][b] = p1;
  __syncthreads();
  if (tid < 128) {
    int cl = tid >> 6;
    int cc = cc0 + cl;
    float p = 0.f;
#pragma unroll
    for (int i = 0; i < 8; ++i) p += red[i][cl][b];
    out[((size_t)b * NAHEAD + srow) * HDIM + cc] = p + b_fc[cc];
  }
}

__global__ __launch_bounds__(256)
void transpose_x(const float* __restrict__ x, float* __restrict__ xT)
{
  __shared__ float tile[64][65];
  const int t = blockIdx.x;
  const int lane = threadIdx.x & 63;
  const int w    = threadIdx.x >> 6;
#pragma unroll
  for (int ii = 0; ii < 16; ++ii) {
    int b = w * 16 + ii;
    tile[b][lane] = x[((size_t)b * TT + t) * IDIM + lane];
  }
  __syncthreads();
#pragma unroll
  for (int ii = 0; ii < 16; ++ii) {
    int i = w * 16 + ii;
    xT[((size_t)t * IDIM + i) * BATCH + lane] = tile[lane][i];
  }
}

// ---------------------------------------------------------------------------
extern "C" void kernel_launch(void* const* d_in, const int* in_sizes, int n_in,
                              void* d_out, int out_size, void* d_ws, size_t ws_size,
                              hipStream_t stream) {
  const float* x     = (const float*)d_in[0];
  const float* w_ih0 = (const float*)d_in[1];
  const float* w_hh0 = (const float*)d_in[2];
  const float* b_ih0 = (const float*)d_in[3];
  const float* b_hh0 = (const float*)d_in[4];
  const float* w_ih1 = (const float*)d_in[5];
  const float* w_hh1 = (const float*)d_in[6];
  const float* b_ih1 = (const float*)d_in[7];
  const float* b_hh1 = (const float*)d_in[8];
  const float* w_ihd = (const float*)d_in[9];
  const float* w_hhd = (const float*)d_in[10];
  const float* b_ihd = (const float*)d_in[11];
  const float* b_hhd = (const float*)d_in[12];
  const float* w_fc  = (const float*)d_in[13];
  const float* b_fc  = (const float*)d_in[14];
  float* out = (float*)d_out;

  char* ws = (char*)d_ws;
  size_t off = 0;
  auto alloc = [&](size_t bytes) -> void* {
    void* p = ws + off;
    off += (bytes + 255) & ~(size_t)255;
    return p;
  };

  float* cst0 = (float*)alloc((size_t)HB * 4);            // zero (fallback)
  float* cst1 = (float*)alloc((size_t)HB * 4);            // final L1 c-state
  float* seq0 = (float*)alloc((size_t)(TT + 1) * HB * 4); // slot0 zero
  float* enc  = (float*)alloc((size_t)(TT + 1) * HB * 4); // slot0 zero
  float* xT   = (float*)alloc((size_t)TT * IDIM * BATCH * 4);
  float* scores = (float*)alloc((size_t)TT * BATCH * 4);
  float* xi     = (float*)alloc((size_t)HB * 4);
  float* hdec   = (float*)alloc((size_t)2 * HB * 4);
  unsigned* flags   = (unsigned*)alloc(256 * 16 * 4);     // encoder barrier
  unsigned* release = (unsigned*)alloc(256);
  (void)ws_size; (void)in_sizes; (void)n_in; (void)out_size;

  hipMemsetAsync(cst0, 0, (size_t)HB * 4 * 2, stream);    // cst0+cst1
  hipMemsetAsync(seq0, 0, (size_t)HB * 4, stream);
  hipMemsetAsync(enc,  0, (size_t)HB * 4, stream);
  hipMemsetAsync(flags, 0, 256 * 16 * 4, stream);
  hipMemsetAsync(release, 0, 256, stream);

  transpose_x<<<TT, 256, 0, stream>>>(x, xT);

  static bool attr_set = false;
  if (!attr_set) {
    hipFuncSetAttribute(reinterpret_cast<const void*>(encoder_coop),
                        hipFuncAttributeMaxDynamicSharedMemorySize,
                        ENC_SMEM_BYTES);
    attr_set = true;
  }

  // ---- encoder: ONE cooperative kernel (round-6/9 verified config) ----
  void* args[] = {
    (void*)&xT,
    (void*)&w_ih0, (void*)&w_hh0, (void*)&b_ih0, (void*)&b_hh0,
    (void*)&w_ih1, (void*)&w_hh1, (void*)&b_ih1, (void*)&b_hh1,
    (void*)&seq0, (void*)&enc, (void*)&cst1, (void*)&flags, (void*)&release
  };
  hipError_t cerr = hipLaunchCooperativeKernel(
      reinterpret_cast<void*>(encoder_coop), dim3(256), dim3(1024),
      args, (unsigned)ENC_SMEM_BYTES, stream);
  if (cerr != hipSuccess) {
    for (int t = 0; t <= TT; ++t) {
      lstm_step<<<256, 1024, 0, stream>>>(
          t, xT, w_ih0, w_hh0, b_ih0, b_hh0,
          w_ih1, w_hh1, b_ih1, b_hh1, seq0, enc, cst0, cst1);
    }
  }

  // ---- decoder: launch-based chain (round-6 verified: ~0.75 ms; the coop
  // decoder measured 1.2-1.3 ms in rounds 8/9 — launches win here) ----
  const float* h_cur = enc + (size_t)TT * HB;
  for (int s = 0; s < NAHEAD; ++s) {
    attn_scores<<<256, 512, 0, stream>>>(enc, h_cur, scores);
    attn_ctx<<<256, 512, 0, stream>>>(enc, scores, h_cur, w_fc, b_fc,
                                      xi, out, s);
    float* h_nxt = hdec + (size_t)(s & 1) * HB;
    dec_gates<<<256, 1024, 0, stream>>>(xi, h_cur, w_ihd, w_hhd,
                                        b_ihd, b_hhd, cst1, h_nxt);
    h_cur = h_nxt;
  }
  fc_out<<<256, 512, 0, stream>>>(h_cur, w_fc, b_fc, out, NAHEAD - 1);
}